// Round 6
// baseline (406.004 us; speedup 1.0000x reference)
//
#include <hip/hip_runtime.h>

// TransformerDecoderLayer forward, bf16-MFMA compute / fp32 accumulate.
// T=1024 S=2048 N=4 E=1024 H=16 HD=64 FF=4096.
// R13: FIX — EPI=1 V-transpose read/store width uint2 -> uint4 (was writing
//      only half of V^T; R11 masked it via workspace persistence across bench
//      iterations, R12's P2/P3 scratch reuse of kbuf/vtbuf unmasked it).
//      Rest identical to R12: gemm8_k depth-3 pipeline; EPI=1 QKV scatter
//      (SA + CA-KV), EPI=2 split-K x4 FFN2; ln_k sums 4 nullable partials.

typedef __bf16 bf16x8 __attribute__((ext_vector_type(8)));
typedef float  f32x4  __attribute__((ext_vector_type(4)));
typedef float  f32x16 __attribute__((ext_vector_type(16)));

#define T_  1024
#define S_  2048
#define NB_ 4
#define E_  1024
#define H_  16
#define HD_ 64
#define FF_ 4096
#define M1_ (T_*NB_)   // 4096 tgt tokens
#define M2_ (S_*NB_)   // 8192 memory tokens
#define LOG2E 1.44269504088896f

__device__ __forceinline__ unsigned short f2bf(float f){
  unsigned int u = __builtin_bit_cast(unsigned int, f);
  u += 0x7fffu + ((u>>16)&1u);           // RNE
  return (unsigned short)(u>>16);
}
__device__ __forceinline__ float bf2f(unsigned short h){
  unsigned int u = ((unsigned int)h)<<16;
  return __builtin_bit_cast(float, u);
}

// async global->LDS, 16 B per lane. LDS dest must be wave-uniform base + lane*16.
__device__ __forceinline__ void gload16(unsigned short* l, const unsigned short* g){
  __builtin_amdgcn_global_load_lds(
      (const __attribute__((address_space(1))) unsigned int*)g,
      (__attribute__((address_space(3))) unsigned int*)l, 16, 0, 0);
}

// v_permlane32_swap_b32: a.hi32lanes <-> b.lo32lanes (both operands updated).
__device__ __forceinline__ void perm32swap(unsigned &a, unsigned &b){
  asm("v_permlane32_swap_b32 %0, %1" : "+v"(a), "+v"(b));
}

// LDS offset (elements) for a 256x32 bf16 tile stored as chunk-permuted
// row-pairs: group = row>>1 (128 B = one full bank sweep), slot-in-group =
// ((row&1)*4 | kchunk) ^ (group&7).  Bijective; frag reads land 2-way.
__device__ __forceinline__ int loff(int row, int kc){
  return ((row>>1)<<6) + (((((row&1)<<2)|kc) ^ ((row>>1)&7))<<3);
}

// ---------------- fused f32 -> bf16 convert (8 segments, one launch) ----------------
struct CvtSeg { const float* s; unsigned short* d; int n4; };
struct CvtArgs { CvtSeg seg[8]; int blk_end[8]; };
__global__ __launch_bounds__(256) void f2b_multi_k(CvtArgs a){
  const int b = blockIdx.x;
  int si = 0;
  #pragma unroll
  for (int i=0;i<8;i++) if (b >= a.blk_end[i]) si = i+1;
  const int base = si ? a.blk_end[si-1] : 0;
  const int i4 = (b - base)*256 + threadIdx.x;
  if (i4 >= a.seg[si].n4) return;
  float4 f = ((const float4*)a.seg[si].s)[i4];
  union { unsigned short u[4]; uint2 v; } t;
  t.u[0]=f2bf(f.x); t.u[1]=f2bf(f.y); t.u[2]=f2bf(f.z); t.u[3]=f2bf(f.w);
  ((uint2*)a.seg[si].d)[i4] = t.v;
}

// ---------------- 256x256 8-wave pipelined GEMM (depth-3, counted vmcnt) ----
// FLAGS: 1=relu (EPI=0 only).
// EPI: 0 = bias(+relu)+bf16 store to Cb.
//      1 = QKV scatter: Q region (cols<nq, *qscale, len Lq) -> qb;
//          K region (nq..nq+nk) -> kb; V region -> transpose -> vtb.
//      2 = split-K via grid.z: z slice of K; z==0 adds bias+res -> P0,
//          z=1..3 raw f32 -> P1f/P2/P3.
// Requires M,N % 256 == 0, (per-z) K % 32 == 0 and >= 128.
template<int FLAGS, int EPI>
__global__ __launch_bounds__(512, 2) void gemm8_k(
    const unsigned short* __restrict__ A, int lda,
    const unsigned short* __restrict__ B, int ldb,
    const float* __restrict__ bias,
    unsigned short* __restrict__ Cb,
    unsigned short* __restrict__ qb, unsigned short* __restrict__ kb,
    unsigned short* __restrict__ vtb,
    const float* __restrict__ res,
    float* __restrict__ P0, float* __restrict__ P1f,
    float* __restrict__ P2, float* __restrict__ P3,
    int M, int N, int K,
    int nq, int nk, int Lq, int Lkv, float qscale)
{
  __shared__ unsigned short smem[2][4][256*32];   // [A/B][slot][tile] = 128 KB
  const int tid  = threadIdx.x;
  const int wave = tid>>6, lane = tid&63;
  const int l15 = lane&15, l4 = lane>>4;

  int bid = blockIdx.x;
  if ((gridDim.x & 7) == 0){ const int cpx = gridDim.x>>3; bid = (bid&7)*cpx + (bid>>3); }
  const int nbm = M>>8;
  const int bm = bid % nbm, bn = bid / nbm;
  const int brow = bm<<8, bcol = bn<<8;
  const int wm0 = (wave>>2)*128, wn = (wave&3)*64;
  const int z   = (EPI==2) ? (int)blockIdx.z : 0;
  const int kh  = (EPI==2) ? (K / (int)gridDim.z) : K;
  const int kbeg = z * kh;
  const int NT  = kh>>5;

  // staging map: thread instr i covers LDS chunk l = i*512 + wave*64 + lane
  // (dest = wave-uniform base + lane*16B); global source is pre-swizzled.
  int ldsl[2]; const unsigned short* pA[2]; const unsigned short* pB[2];
  #pragma unroll
  for (int i=0;i<2;i++){
    const int l = i*512 + wave*64 + lane;
    const int grp = l>>3, sl = (l&7) ^ (grp&7);
    const int row = (grp<<1)|(sl>>2), c = sl&3;
    ldsl[i] = l<<3;                                  // element offset
    pA[i] = A + (size_t)(brow + row)*lda + kbeg + (c<<3);
    pB[i] = B + (size_t)(bcol + row)*ldb + kbeg + (c<<3);
  }

  f32x4 acc[8][4] = {};

  auto stageA = [&](int t){
    unsigned short* s = smem[0][t&3];
    #pragma unroll
    for (int i=0;i<2;i++) gload16(&s[ldsl[i]], pA[i] + t*32);
  };
  auto stageB = [&](int t){
    unsigned short* s = smem[1][t&3];
    #pragma unroll
    for (int i=0;i<2;i++) gload16(&s[ldsl[i]], pB[i] + t*32);
  };

  // prologue: tiles 0,1,2 in flight (12 loads); vmcnt(8) lands tile 0.
  stageA(0); stageB(0); stageA(1); stageB(1); stageA(2); stageB(2);
  asm volatile("s_waitcnt vmcnt(8)" ::: "memory");
  __builtin_amdgcn_s_barrier();

  // invariant at top of iter t: tile t landed; t+1,t+2 in flight (8 loads).
  for (int t=0; t<NT; ++t){
    const unsigned short* as = smem[0][t&3];
    const unsigned short* bs = smem[1][t&3];
    const bool pre = (t+3 < NT);

    // ---- phase a: stage A(t+3) || read B + A-lo || MFMA lo-quadrants ----
    if (pre) stageA(t+3);
    bf16x8 bf[4], af[4];
    #pragma unroll
    for (int n=0;n<4;n++) bf[n] = *(const bf16x8*)&bs[loff(wn + n*16 + l15, l4)];
    #pragma unroll
    for (int m=0;m<4;m++) af[m] = *(const bf16x8*)&as[loff(wm0 + m*16 + l15, l4)];
    __builtin_amdgcn_s_barrier();
    __builtin_amdgcn_s_setprio(1);
    #pragma unroll
    for (int m=0;m<4;m++)
      #pragma unroll
      for (int n=0;n<4;n++)
        acc[m][n] = __builtin_amdgcn_mfma_f32_16x16x32_bf16(af[m], bf[n], acc[m][n], 0,0,0);
    __builtin_amdgcn_s_setprio(0);
    __builtin_amdgcn_s_barrier();

    // ---- phase b: stage B(t+3) || read A-hi || MFMA hi-quadrants ----
    if (pre) stageB(t+3);
    #pragma unroll
    for (int m=0;m<4;m++) af[m] = *(const bf16x8*)&as[loff(wm0 + 64 + m*16 + l15, l4)];
    __builtin_amdgcn_s_barrier();
    __builtin_amdgcn_s_setprio(1);
    #pragma unroll
    for (int m=0;m<4;m++)
      #pragma unroll
      for (int n=0;n<4;n++)
        acc[4+m][n] = __builtin_amdgcn_mfma_f32_16x16x32_bf16(af[m], bf[n], acc[4+m][n], 0,0,0);
    __builtin_amdgcn_s_setprio(0);
    if (pre)            asm volatile("s_waitcnt vmcnt(8)" ::: "memory");  // tile t+1 landed
    else if (t+2 < NT)  asm volatile("s_waitcnt vmcnt(4)" ::: "memory");  // tile t+1 landed (tail)
    else                asm volatile("s_waitcnt vmcnt(0)" ::: "memory");  // final drain
    __builtin_amdgcn_s_barrier();
  }

  if constexpr (EPI == 0){
    // C/D layout: col = lane&15, row = (lane>>4)*4 + r
    #pragma unroll
    for (int mi=0;mi<8;mi++){
      #pragma unroll
      for (int r=0;r<4;r++){
        const int rr = brow + wm0 + mi*16 + l4*4 + r;
        #pragma unroll
        for (int n=0;n<4;n++){
          const int cc = bcol + wn + n*16 + l15;
          float v = acc[mi][n][r] + bias[cc];
          if (FLAGS & 1) v = fmaxf(v, 0.f);
          Cb[(size_t)rr*N + cc] = f2bf(v);
        }
      }
    }
  } else if constexpr (EPI == 1){
    const int voff = nq + nk;
    if (bcol < voff){
      // ---- Q/K-region: scatter to {qb|kb}[((nn*H+h)*L + t)*HD + d] ----
      const bool isq = (bcol < nq);
      unsigned short* dst = isq ? qb : kb;
      const int  base  = isq ? 0 : nq;
      const int  L     = isq ? Lq : Lkv;
      const float scale = isq ? qscale : 1.0f;
      #pragma unroll
      for (int mi=0;mi<8;mi++){
        #pragma unroll
        for (int r=0;r<4;r++){
          const int rr = brow + wm0 + mi*16 + l4*4 + r;
          const int t = rr>>2, nn = rr&3;
          #pragma unroll
          for (int n=0;n<4;n++){
            const int cc = bcol + wn + n*16 + l15;
            const int e = cc - base, h = e>>6, d = e&63;
            dst[((size_t)(nn*H_ + h)*L + t)*HD_ + d] = f2bf((acc[mi][n][r] + bias[cc])*scale);
          }
        }
      }
    } else {
      // ---- V-region: transpose through LDS, then 16B chunk writes ----
      unsigned short* cT = &smem[0][0][0];   // 65536 elems = whole 128 KB
      #pragma unroll
      for (int mi=0;mi<8;mi++){
        const int tl = (wm0>>2) + mi*4 + l4;   // token-local 0..63
        #pragma unroll
        for (int n=0;n<4;n++){
          const int ccl = wn + n*16 + l15;
          const float bi = bias[bcol + ccl];
          #pragma unroll
          for (int r=0;r<4;r++){               // r == batch index nn
            const int unit = r*8 + (tl>>3);
            cT[ccl*256 + ((unit ^ (ccl&7))<<3) + (tl&7)] = f2bf(acc[mi][n][r] + bi);
          }
        }
      }
      __syncthreads();
      const int t0 = brow>>2;
      #pragma unroll
      for (int i=0;i<16;i++){
        const int ch = i*512 + tid;
        const int tl8 = ch&7, nn = (ch>>3)&3, ccl = ch>>5;
        const int e = bcol - voff + ccl, h = e>>6, d = e&63;
        const int unit = (nn<<3) | tl8;
        // R13 fix: full 8-element unit (uint4 = 16 B), was uint2 (half-write).
        const uint4 v = *(const uint4*)&cT[ccl*256 + ((unit ^ (ccl&7))<<3)];
        *(uint4*)(vtb + ((size_t)(nn*H_ + h)*HD_ + d)*Lkv + t0 + tl8*8) = v;
      }
    }
  } else {
    // ---- EPI==2: split-K f32 partial stores ----
    float* out = (z==0) ? P0 : (z==1) ? P1f : (z==2) ? P2 : P3;
    #pragma unroll
    for (int mi=0;mi<8;mi++){
      #pragma unroll
      for (int r=0;r<4;r++){
        const int rr = brow + wm0 + mi*16 + l4*4 + r;
        #pragma unroll
        for (int n=0;n<4;n++){
          const int cc = bcol + wn + n*16 + l15;
          float v = acc[mi][n][r];
          if (z == 0) v += bias[cc] + res[(size_t)rr*N + cc];
          out[(size_t)rr*N + cc] = v;
        }
      }
    }
  }
}

// -------- split-K x2 GEMM (grid.z in {0,1}); z=0: +bias+res -> P0, z=1: raw -> P1 --------
template<int BN>
__global__ __launch_bounds__(256) void gemm_splitk_k(
    const unsigned short* __restrict__ A, int lda,
    const unsigned short* __restrict__ B, int ldb,
    const float* __restrict__ bias,
    const float* __restrict__ res,
    float* __restrict__ P0, float* __restrict__ P1,
    int M, int N, int K)
{
  constexpr int NW = BN/32;
  __shared__ unsigned short a_sh[128*64];
  __shared__ unsigned short b_sh[BN*64];
  const int tid  = threadIdx.x;
  const int wave = tid>>6;
  const int lane = tid&63;
  const int l15 = lane&15, l4 = lane>>4;
  const int row0 = blockIdx.x*128, col0 = blockIdx.y*BN;
  const int wm = (wave>>1)*64, wn = (wave&1)*(BN/2);
  const int z = blockIdx.z;
  const int kh = K>>1;
  const int kbeg = z*kh;

  const int lrow = tid>>3;
  const int scol = ((tid&7) ^ (lrow&7)) << 3;
  const int dst8 = (tid&7) << 3;

  f32x4 acc[4][NW] = {};

  for (int k0=kbeg; k0<kbeg+kh; k0+=64){
    const unsigned short* ga = A + (size_t)(row0+lrow)*lda + k0 + scol;
    const unsigned short* gb = B + (size_t)(col0+lrow)*ldb + k0 + scol;
    #pragma unroll
    for (int i=0;i<4;i++)
      gload16(&a_sh[(lrow + i*32)*64 + dst8], ga + (size_t)(i*32)*lda);
    #pragma unroll
    for (int i=0;i<BN/32;i++)
      gload16(&b_sh[(lrow + i*32)*64 + dst8], gb + (size_t)(i*32)*ldb);
    __syncthreads();
    #pragma unroll
    for (int kk=0;kk<2;kk++){
      const int sw = (((kk<<2)|l4) ^ (l15&7)) << 3;
      bf16x8 af[4], bfr[NW];
      #pragma unroll
      for (int m=0;m<4;m++)  af[m]  = *(const bf16x8*)&a_sh[(wm + m*16 + l15)*64 + sw];
      #pragma unroll
      for (int n=0;n<NW;n++) bfr[n] = *(const bf16x8*)&b_sh[(wn + n*16 + l15)*64 + sw];
      #pragma unroll
      for (int m=0;m<4;m++)
        #pragma unroll
        for (int n=0;n<NW;n++)
          acc[m][n] = __builtin_amdgcn_mfma_f32_16x16x32_bf16(af[m], bfr[n], acc[m][n], 0,0,0);
    }
    __syncthreads();
  }

  float* out = z ? P1 : P0;
  #pragma unroll
  for (int m=0;m<4;m++){
    #pragma unroll
    for (int r=0;r<4;r++){
      const int rr = row0 + wm + m*16 + l4*4 + r;
      #pragma unroll
      for (int n=0;n<NW;n++){
        const int cc = col0 + wn + n*16 + l15;
        float v = acc[m][n][r];
        if (!z) v += bias[cc] + res[(size_t)rr*N + cc];
        out[(size_t)rr*N + cc] = v;
      }
    }
  }
}

// -------- QKV-projection GEMM with fused scatter epilogue (CA-Q only now) --------
template<int BN>
__global__ __launch_bounds__(256) void gemm_scat_k(
    const unsigned short* __restrict__ A, int lda,
    const unsigned short* __restrict__ B, int ldb,
    const float* __restrict__ bias,
    unsigned short* __restrict__ qb, unsigned short* __restrict__ kb,
    unsigned short* __restrict__ vtb,
    int M, int N, int K, int nq, int nk, int Lq, int Lkv, float qscale)
{
  constexpr int NW = BN/32;
  constexpr int SMEM_ELEMS = (BN==128) ? (128*132) : (128*64 + BN*64);
  __shared__ unsigned short smem[SMEM_ELEMS];
  unsigned short* a_sh = smem;
  unsigned short* b_sh = smem + 128*64;
  const int tid  = threadIdx.x;
  const int wave = tid>>6, lane = tid&63;
  const int l15 = lane&15, l4 = lane>>4;
  const int row0 = blockIdx.x*128, col0 = blockIdx.y*BN;
  const int wm = (wave>>1)*64, wn = (wave&1)*(BN/2);

  const int lrow = tid>>3;
  const int scol = ((tid&7) ^ (lrow&7)) << 3;
  const int dst8 = (tid&7) << 3;

  f32x4 acc[4][NW] = {};

  for (int k0=0; k0<K; k0+=64){
    const unsigned short* ga = A + (size_t)(row0+lrow)*lda + k0 + scol;
    const unsigned short* gb = B + (size_t)(col0+lrow)*ldb + k0 + scol;
    #pragma unroll
    for (int i=0;i<4;i++)
      gload16(&a_sh[(lrow + i*32)*64 + dst8], ga + (size_t)(i*32)*lda);
    #pragma unroll
    for (int i=0;i<BN/32;i++)
      gload16(&b_sh[(lrow + i*32)*64 + dst8], gb + (size_t)(i*32)*ldb);
    __syncthreads();
    #pragma unroll
    for (int kk=0;kk<2;kk++){
      const int sw = (((kk<<2)|l4) ^ (l15&7)) << 3;
      bf16x8 af[4], bfr[NW];
      #pragma unroll
      for (int m=0;m<4;m++)  af[m]  = *(const bf16x8*)&a_sh[(wm + m*16 + l15)*64 + sw];
      #pragma unroll
      for (int n=0;n<NW;n++) bfr[n] = *(const bf16x8*)&b_sh[(wn + n*16 + l15)*64 + sw];
      #pragma unroll
      for (int m=0;m<4;m++)
        #pragma unroll
        for (int n=0;n<NW;n++)
          acc[m][n] = __builtin_amdgcn_mfma_f32_16x16x32_bf16(af[m], bfr[n], acc[m][n], 0,0,0);
    }
    __syncthreads();
  }

  if (col0 < nq + nk){
    const bool isq = (col0 < nq);
    unsigned short* dst = isq ? qb : kb;
    const int  base  = isq ? 0 : nq;
    const int  L     = isq ? Lq : Lkv;
    const float scale = isq ? qscale : 1.0f;
    #pragma unroll
    for (int m=0;m<4;m++){
      #pragma unroll
      for (int r=0;r<4;r++){
        const int rr = row0 + wm + m*16 + l4*4 + r;
        const int t = rr>>2, nn = rr&3;
        #pragma unroll
        for (int n=0;n<NW;n++){
          const int cc = col0 + wn + n*16 + l15;
          const int e = cc - base, h = e>>6, d = e&63;
          const float v = (acc[m][n][r] + bias[cc]) * scale;
          dst[((size_t)(nn*H_ + h)*L + t)*HD_ + d] = f2bf(v);
        }
      }
    }
  }
}

// ---------------- flash attention, 32x32 swapped-QK^T, max-free softmax ----
// R9: pipelined  QK(i) -> PV(i-1) -> softmax(i); pa double-buffered; skewed
//     K/V staging with counted vmcnt(4).
template<bool PARTIAL, int NT>
__global__ __launch_bounds__(256,3) void attn_k(
    const unsigned short* __restrict__ qb, const unsigned short* __restrict__ kb,
    const unsigned short* __restrict__ vtb,
    unsigned short* __restrict__ o_out, float* __restrict__ l_out,
    int T, int S)
{
  static_assert((NT & 1) == 0 && NT >= 4, "NT even");
  __shared__ unsigned short k_sh[2][64*64];   // [slot][key][d] swizzled
  __shared__ unsigned short v_sh[2][64*64];   // [slot][d][key] swizzled (V^T)
  __shared__ float bc_sh[4][32];              // per-wave per-qrow broadcast (final mode)
  const int tid  = threadIdx.x;
  const int wave = tid>>6, lane = tid&63;
  const int l31  = lane&31;
  const int hv   = lane>>5;                // lane half
  const int bh   = blockIdx.x;             // batch-head
  const int z    = blockIdx.z;
  const int s_begin = z * (NT*64);
  const int q0   = blockIdx.y*128 + wave*32;
  const size_t qbase = (size_t)bh*T*HD_;
  const size_t kbase = (size_t)bh*S*HD_;
  const size_t vbase = (size_t)bh*HD_*S;

  const int strow = tid>>3;                // 0..31
  const int stch  = tid&7;
  const int sc_sw = (stch ^ (strow&7)) << 3;  // (row&7)==((row+32)&7) -> same swizzle
  const int dst8  = stch<<3;
  const unsigned short* gk0 = kb  + kbase + (size_t)s_begin*HD_;
  const unsigned short* gv0 = vtb + vbase + s_begin;

  auto stageK = [&](int t, int slot){
    const unsigned short* g = gk0 + (size_t)(t*64)*HD_;
    gload16(&k_sh[slot][(strow   )*64 + dst8], g + (size_t)(strow   )*HD_ + sc_sw);
    gload16(&k_sh[slot][(strow+32)*64 + dst8], g + (size_t)(strow+32)*HD_ + sc_sw);
  };
  auto stageV = [&](int t, int slot){
    const unsigned short* g = gv0 + t*64;
    gload16(&v_sh[slot][(strow   )*64 + dst8], g + (size_t)(strow   )*S + sc_sw);
    gload16(&v_sh[slot][(strow+32)*64 + dst8], g + (size_t)(strow+32)*S + sc_sw);
  };

  // ---- Q fragments first (fixed position in the vmcnt stream) ----
  bf16x8 qf[4];
  #pragma unroll
  for (int p=0;p<4;p++)
    qf[p] = *(const bf16x8*)(qb + qbase + (size_t)(q0 + l31)*HD_ + p*16 + hv*8);
  asm volatile("" ::: "memory");   // pin Q loads before staging in issue order

  // ---- prologue: K(0) ----
  stageK(0, 0);

  f32x16 o0 = {}, o1 = {};
  float rsa = 0.f, rsb = 0.f;
  bf16x8 paA[4], paB[4];

  auto QK = [&](const unsigned short* ksh, f32x16& s0, f32x16& s1){
    #pragma unroll
    for (int p=0;p<4;p++){
      const int slot = 2*p + hv;
      bf16x8 kf0 = *(const bf16x8*)&ksh[(l31     )*64 + ((slot ^ (l31&7))<<3)];
      bf16x8 kf1 = *(const bf16x8*)&ksh[(l31 + 32)*64 + ((slot ^ (l31&7))<<3)];
      s0 = __builtin_amdgcn_mfma_f32_32x32x16_bf16(kf0, qf[p], s0, 0,0,0);
      s1 = __builtin_amdgcn_mfma_f32_32x32x16_bf16(kf1, qf[p], s1, 0,0,0);
    }
  };
  auto PV = [&](const unsigned short* vsh, const bf16x8* pa){
    #pragma unroll
    for (int ks=0;ks<4;ks++){
      const int slot = 2*ks + hv;
      bf16x8 vf0 = *(const bf16x8*)&vsh[(l31     )*64 + ((slot ^ (l31&7))<<3)];
      bf16x8 vf1 = *(const bf16x8*)&vsh[(l31 + 32)*64 + ((slot ^ (l31&7))<<3)];
      o0 = __builtin_amdgcn_mfma_f32_32x32x16_bf16(pa[ks], vf0, o0, 0,0,0);
      o1 = __builtin_amdgcn_mfma_f32_32x32x16_bf16(pa[ks], vf1, o1, 0,0,0);
    }
  };
  auto SM = [&](f32x16& s0, f32x16& s1, bf16x8* pa){
    #pragma unroll
    for (int r=0;r<16;r++){
      s0[r] = __builtin_amdgcn_exp2f(s0[r]);
      s1[r] = __builtin_amdgcn_exp2f(s1[r]);
    }
    #pragma unroll
    for (int r=0;r<16;r+=2){
      rsa += s0[r]   + s1[r];
      rsb += s0[r+1] + s1[r+1];
    }
    #pragma unroll
    for (int ks=0;ks<4;ks++){
      const int base = 8*(ks&1);
      unsigned pkA0, pkA1, pkB0, pkB1;
      if (ks < 2){
        asm("v_cvt_pk_bf16_f32 %0, %1, %2" : "=v"(pkA0) : "v"(s0[base+0]), "v"(s0[base+1]));
        asm("v_cvt_pk_bf16_f32 %0, %1, %2" : "=v"(pkA1) : "v"(s0[base+2]), "v"(s0[base+3]));
        asm("v_cvt_pk_bf16_f32 %0, %1, %2" : "=v"(pkB0) : "v"(s0[base+4]), "v"(s0[base+5]));
        asm("v_cvt_pk_bf16_f32 %0, %1, %2" : "=v"(pkB1) : "v"(s0[base+6]), "v"(s0[base+7]));
      } else {
        asm("v_cvt_pk_bf16_f32 %0, %1, %2" : "=v"(pkA0) : "v"(s1[base+0]), "v"(s1[base+1]));
        asm("v_cvt_pk_bf16_f32 %0, %1, %2" : "=v"(pkA1) : "v"(s1[base+2]), "v"(s1[base+3]));
        asm("v_cvt_pk_bf16_f32 %0, %1, %2" : "=v"(pkB0) : "v"(s1[base+4]), "v"(s1[base+5]));
        asm("v_cvt_pk_bf16_f32 %0, %1, %2" : "=v"(pkB1) : "v"(s1[base+6]), "v"(s1[base+7]));
      }
      perm32swap(pkA0, pkB0);
      perm32swap(pkA1, pkB1);
      union { unsigned w[4]; bf16x8 v; } u;
      u.w[0] = pkA0; u.w[1] = pkA1; u.w[2] = pkB0; u.w[3] = pkB1;
      pa[ks] = u.v;
    }
  };

  // ---- iter 0 (peeled: no PV) ----
  {
    stageK(1, 1);
    stageV(0, 0);
    asm volatile("s_waitcnt vmcnt(4)" ::: "memory");   // drain K(0) + Q
    __builtin_amdgcn_s_barrier();
    f32x16 s0 = {}, s1 = {};
    __builtin_amdgcn_s_setprio(1);
    QK(k_sh[0], s0, s1);
    __builtin_amdgcn_s_setprio(0);
    SM(s0, s1, paA);
    __builtin_amdgcn_s_barrier();
  }

  auto BODY = [&](int i, const bf16x8* paPrev, bf16x8* paCur){
    const int kt = (i+1 < NT) ? (i+1) : (NT-1);       // clamped prefetch
    stageK(kt, (i+1)&1);
    stageV(i, i&1);
    asm volatile("s_waitcnt vmcnt(4)" ::: "memory");   // drain K(i), V(i-1)
    __builtin_amdgcn_s_barrier();
    f32x16 s0 = {}, s1 = {};
    __builtin_amdgcn_s_setprio(1);
    QK(k_sh[i&1], s0, s1);
    PV(v_sh[(i+1)&1], paPrev);                         // (i-1)&1 == (i+1)&1
    __builtin_amdgcn_s_setprio(0);
    SM(s0, s1, paCur);
    __builtin_amdgcn_s_barrier();
  };

  for (int ii=1; ii+1<NT; ii+=2){
    BODY(ii,   paA, paB);
    BODY(ii+1, paB, paA);
  }
  BODY(NT-1, paA, paB);

  // ---- epilogue: PV of last tile ----
  asm volatile("s_waitcnt vmcnt(0)" ::: "memory");
  __builtin_amdgcn_s_barrier();
  __builtin_amdgcn_s_setprio(1);
  PV(v_sh[(NT-1)&1], paB);
  __builtin_amdgcn_s_setprio(0);

  // ---- finalize l: one cross-half swap ----
  float l_run = rsa + rsb;
  {
    unsigned a_ = __builtin_bit_cast(unsigned, l_run), b_ = a_;
    perm32swap(a_, b_);
    l_run += __builtin_bit_cast(float, hv ? a_ : b_);
  }

  if constexpr (PARTIAL){
    const size_t obase = (size_t)(z*64 + bh)*T;
    #pragma unroll
    for (int r=0;r<16;r++){
      const int qr = (r&3) + 8*(r>>2) + 4*hv;
      unsigned short* op = o_out + (obase + q0 + qr)*HD_;
      op[l31]      = f2bf(o0[r]);
      op[l31 + 32] = f2bf(o1[r]);
    }
    if (hv == 0) l_out[obase + q0 + l31] = l_run;
  } else {
    bc_sh[wave][l31] = 1.f / l_run;
    const int nb = bh>>4, hh = bh&15;
    #pragma unroll
    for (int r=0;r<16;r++){
      const int qr  = (r&3) + 8*(r>>2) + 4*hv;
      const float inv = bc_sh[wave][qr];
      const int t = q0 + qr;
      unsigned short* op = o_out + ((size_t)t*NB_ + nb)*E_ + hh*HD_;
      op[l31]      = f2bf(o0[r]*inv);
      op[l31 + 32] = f2bf(o1[r]*inv);
    }
  }
}

// ---------------- combine split-KV partials ----------------
__global__ __launch_bounds__(256) void comb_k(
    const unsigned short* __restrict__ opart, const float* __restrict__ lpart,
    unsigned short* __restrict__ outb, int T)
{
  const int bh = blockIdx.y;
  const int t  = blockIdx.x*4 + (threadIdx.x>>6);
  const int d  = threadIdx.x&63;
  const size_t half = (size_t)64*T;
  const size_t row  = (size_t)bh*T + t;
  const float o = bf2f(opart[row*HD_ + d]) + bf2f(opart[(half + row)*HD_ + d]);
  const float l = lpart[row] + lpart[half + row];
  const int nb = bh>>4, hh = bh&15;
  outb[((size_t)t*NB_ + nb)*E_ + hh*HD_ + d] = f2bf(o / l);
}

// ---------------- LayerNorm over E=1024 of (p0+p1[+p2][+p3]), one block/row ----
__global__ __launch_bounds__(256) void ln_k(
    const float* __restrict__ p0, const float* __restrict__ p1,
    const float* __restrict__ p2, const float* __restrict__ p3,
    const float* __restrict__ g, const float* __restrict__ bb,
    float* __restrict__ of, unsigned short* __restrict__ ob)
{
  const int row = blockIdx.x, tid = threadIdx.x;
  const size_t base = (size_t)row*E_;
  float v[4];
  #pragma unroll
  for (int i=0;i<4;i++){
    const int col = tid + 256*i;
    v[i] = p0[base + col] + p1[base + col];
    if (p2) v[i] += p2[base + col];
    if (p3) v[i] += p3[base + col];
  }
  float s  = v[0]+v[1]+v[2]+v[3];
  float s2 = v[0]*v[0]+v[1]*v[1]+v[2]*v[2]+v[3]*v[3];
  #pragma unroll
  for (int off=32; off>0; off>>=1){
    s  += __shfl_down(s, off);
    s2 += __shfl_down(s2, off);
  }
  __shared__ float red[8];
  if ((tid&63)==0){ red[tid>>6] = s; red[4+(tid>>6)] = s2; }
  __syncthreads();
  s  = red[0]+red[1]+red[2]+red[3];
  s2 = red[4]+red[5]+red[6]+red[7];
  const float mu   = s * (1.f/E_);
  const float var  = s2 * (1.f/E_) - mu*mu;
  const float rstd = rsqrtf(var + 1e-5f);
  #pragma unroll
  for (int i=0;i<4;i++){
    const int col = tid + 256*i;
    const float y = (v[i]-mu)*rstd*g[col] + bb[col];
    if (of) of[base + col] = y;
    if (ob) ob[base + col] = f2bf(y);
  }
}

// ---------------- driver ----------------
extern "C" void kernel_launch(void* const* d_in, const int* in_sizes, int n_in,
                              void* d_out, int out_size, void* d_ws, size_t ws_size,
                              hipStream_t stream)
{
  const float* tgt      = (const float*)d_in[0];
  const float* mem      = (const float*)d_in[1];
  const float* sa_w_in  = (const float*)d_in[2];
  const float* sa_b_in  = (const float*)d_in[3];
  const float* sa_w_out = (const float*)d_in[4];
  const float* sa_b_out = (const float*)d_in[5];
  const float* ca_w_in  = (const float*)d_in[6];
  const float* ca_b_in  = (const float*)d_in[7];
  const float* ca_w_out = (const float*)d_in[8];
  const float* ca_b_out = (const float*)d_in[9];
  const float* w1 = (const float*)d_in[10];
  const float* b1 = (const float*)d_in[11];
  const float* w2 = (const float*)d_in[12];
  const float* b2 = (const float*)d_in[13];
  const float* ln1_g=(const float*)d_in[14]; const float* ln1_b=(const float*)d_in[15];
  const float* ln2_g=(const float*)d_in[16]; const float* ln2_b=(const float*)d_in[17];
  const float* ln3_g=(const float*)d_in[18]; const float* ln3_b=(const float*)d_in[19];

  char* ws = (char*)d_ws;
  size_t off = 0;
  auto alloc = [&](size_t bytes)->char* {
    char* p = ws + off; off += (bytes + 255) & ~(size_t)255; return p;
  };
  unsigned short* w_sa_in_b  = (unsigned short*)alloc((size_t)3*E_*E_*2);
  unsigned short* w_sa_out_b = (unsigned short*)alloc((size_t)E_*E_*2);
  unsigned short* w_ca_in_b  = (unsigned short*)alloc((size_t)3*E_*E_*2);
  unsigned short* w_ca_out_b = (unsigned short*)alloc((size_t)E_*E_*2);
  unsigned short* w1_b  = (unsigned short*)alloc((size_t)FF_*E_*2);
  unsigned short* w2_b  = (unsigned short*)alloc((size_t)E_*FF_*2);
  unsigned short* tgt_b = (unsigned short*)alloc((size_t)M1_*E_*2);
  unsigned short* mem_b = (unsigned short*)alloc((size_t)M2_*E_*2);
  unsigned short* qbuf  = (unsigned short*)alloc((size_t)64*T_*HD_*2);
  unsigned short* kbuf  = (unsigned short*)alloc((size_t)64*S_*HD_*2);
  unsigned short* vtbuf = (unsigned short*)alloc((size_t)64*S_*HD_*2);
  unsigned short* cbuf  = (unsigned short*)alloc((size_t)M1_*FF_*2);
  unsigned short* atto  = (unsigned short*)alloc((size_t)M1_*E_*2);
  unsigned short* opart = (unsigned short*)alloc((size_t)2*64*T_*HD_*2);  // also reused as f32 P1 (16 MB)
  float*          lpart = (float*)alloc((size_t)2*64*T_*4);
  float* resf = (float*)alloc((size_t)M1_*E_*4);
  float* xf   = (float*)alloc((size_t)M1_*E_*4);
  unsigned short* xb = (unsigned short*)alloc((size_t)M1_*E_*2);
  (void)ws_size; (void)in_sizes; (void)n_in; (void)out_size;

  float* P1 = (float*)opart;   // 2*64*1024*64*2 B == M1_*E_*4 B exactly
  float* P2 = (float*)kbuf;    // 16 MB each, free during FFN (attn done)
  float* P3 = (float*)vtbuf;

  const float QSCALE = 0.125f * LOG2E;   // fold log2e into q so P = exp2(score)

  // ---- fused input/weight conversion (one launch) ----
  {
    CvtArgs a;
    const float* srcs[8] = {tgt, mem, sa_w_in, sa_w_out, ca_w_in, ca_w_out, w1, w2};
    unsigned short* dsts[8] = {tgt_b, mem_b, w_sa_in_b, w_sa_out_b, w_ca_in_b, w_ca_out_b, w1_b, w2_b};
    size_t ns[8] = {(size_t)M1_*E_, (size_t)M2_*E_, (size_t)3*E_*E_, (size_t)E_*E_,
                    (size_t)3*E_*E_, (size_t)E_*E_, (size_t)FF_*E_, (size_t)E_*FF_};
    int blk = 0;
    for (int i=0;i<8;i++){
      a.seg[i].s = srcs[i]; a.seg[i].d = dsts[i]; a.seg[i].n4 = (int)(ns[i]/4);
      blk += (a.seg[i].n4 + 255)/256;
      a.blk_end[i] = blk;
    }
    f2b_multi_k<<<blk, 256, 0, stream>>>(a);
  }

  // ---- self-attention block ----
  gemm8_k<0,1><<<(M1_/256)*((3*E_)/256), 512, 0, stream>>>(
      tgt_b, E_, w_sa_in_b, E_, sa_b_in, nullptr, qbuf, kbuf, vtbuf,
      nullptr, nullptr, nullptr, nullptr, nullptr,
      M1_, 3*E_, E_, E_, E_, T_, T_, QSCALE);
  attn_k<false,16><<<dim3(64, T_/128, 1), 256, 0, stream>>>(
      qbuf, kbuf, vtbuf, atto, nullptr, T_, T_);
  gemm_splitk_k<64><<<dim3(M1_/128, E_/64, 2), 256, 0, stream>>>(
      atto, E_, w_sa_out_b, E_, sa_b_out, tgt, resf, P1, M1_, E_, E_);
  ln_k<<<M1_, 256, 0, stream>>>(resf, P1, nullptr, nullptr, ln1_g, ln1_b, xf, xb);

  // ---- cross-attention block ----
  gemm8_k<0,1><<<(M2_/256)*((2*E_)/256), 512, 0, stream>>>(
      mem_b, E_, w_ca_in_b + (size_t)E_*E_, E_, ca_b_in + E_, nullptr,
      nullptr, kbuf, vtbuf,
      nullptr, nullptr, nullptr, nullptr, nullptr,
      M2_, 2*E_, E_, 0, E_, S_, S_, QSCALE);
  gemm_scat_k<64><<<dim3(M1_/128, E_/64), 256, 0, stream>>>(
      xb, E_, w_ca_in_b, E_, ca_b_in, qbuf, nullptr, nullptr,
      M1_, E_, E_, E_, 0, T_, S_, QSCALE);
  attn_k<true,16><<<dim3(64, T_/128, 2), 256, 0, stream>>>(
      qbuf, kbuf, vtbuf, opart, lpart, T_, S_);
  comb_k<<<dim3(T_/4, 64), 256, 0, stream>>>(opart, lpart, atto, T_);
  gemm_splitk_k<64><<<dim3(M1_/128, E_/64, 2), 256, 0, stream>>>(
      atto, E_, w_ca_out_b, E_, ca_b_out, xf, resf, P1, M1_, E_, E_);
  ln_k<<<M1_, 256, 0, stream>>>(resf, P1, nullptr, nullptr, ln2_g, ln2_b, xf, xb);

  // ---- FFN ----
  gemm8_k<5,0><<<(M1_/256)*(FF_/256), 512, 0, stream>>>(
      xb, E_, w1_b, E_, b1, cbuf, nullptr, nullptr, nullptr,
      nullptr, nullptr, nullptr, nullptr, nullptr,
      M1_, FF_, E_, 0, 0, 0, 0, 0.f);
  gemm8_k<0,2><<<dim3((M1_/256)*(E_/256), 1, 4), 512, 0, stream>>>(
      cbuf, FF_, w2_b, FF_, b2, nullptr, nullptr, nullptr, nullptr,
      xf, resf, P1, P2, P3,
      M1_, E_, FF_, 0, 0, 0, 0, 0.f);
  ln_k<<<M1_, 256, 0, stream>>>(resf, P1, P2, P3, ln3_g, ln3_b, (float*)d_out, nullptr);
}

// Round 7
// 380.290 us; speedup vs baseline: 1.0676x; 1.0676x over previous
//
#include <hip/hip_runtime.h>

// TransformerDecoderLayer forward, bf16-MFMA compute / fp32 accumulate.
// T=1024 S=2048 N=4 E=1024 H=16 HD=64 FF=4096.
// R14: revert FFN2 to gemm_splitk_k x2 (R13's EPI=2 split-K x4 was memory-
//      bound on 64 MB f32 partial traffic: 74us vs 49.5us) + ln3 back to
//      2 partials. gemm_splitk_k retrofitted with the R8-proven pipeline:
//      double-buffered LDS, prefetch t+1, counted s_waitcnt vmcnt(6) + raw
//      s_barrier (no per-iter full drain), setprio around MFMA.
//      gemm8 (FFN1 EPI=0, SA-QKV/CA-KV EPI=1) and attn_k unchanged from R13.

typedef __bf16 bf16x8 __attribute__((ext_vector_type(8)));
typedef float  f32x4  __attribute__((ext_vector_type(4)));
typedef float  f32x16 __attribute__((ext_vector_type(16)));

#define T_  1024
#define S_  2048
#define NB_ 4
#define E_  1024
#define H_  16
#define HD_ 64
#define FF_ 4096
#define M1_ (T_*NB_)   // 4096 tgt tokens
#define M2_ (S_*NB_)   // 8192 memory tokens
#define LOG2E 1.44269504088896f

__device__ __forceinline__ unsigned short f2bf(float f){
  unsigned int u = __builtin_bit_cast(unsigned int, f);
  u += 0x7fffu + ((u>>16)&1u);           // RNE
  return (unsigned short)(u>>16);
}
__device__ __forceinline__ float bf2f(unsigned short h){
  unsigned int u = ((unsigned int)h)<<16;
  return __builtin_bit_cast(float, u);
}

// async global->LDS, 16 B per lane. LDS dest must be wave-uniform base + lane*16.
__device__ __forceinline__ void gload16(unsigned short* l, const unsigned short* g){
  __builtin_amdgcn_global_load_lds(
      (const __attribute__((address_space(1))) unsigned int*)g,
      (__attribute__((address_space(3))) unsigned int*)l, 16, 0, 0);
}

// v_permlane32_swap_b32: a.hi32lanes <-> b.lo32lanes (both operands updated).
__device__ __forceinline__ void perm32swap(unsigned &a, unsigned &b){
  asm("v_permlane32_swap_b32 %0, %1" : "+v"(a), "+v"(b));
}

// LDS offset (elements) for a 256x32 bf16 tile stored as chunk-permuted
// row-pairs: group = row>>1 (128 B = one full bank sweep), slot-in-group =
// ((row&1)*4 | kchunk) ^ (group&7).  Bijective; frag reads land 2-way.
__device__ __forceinline__ int loff(int row, int kc){
  return ((row>>1)<<6) + (((((row&1)<<2)|kc) ^ ((row>>1)&7))<<3);
}

// ---------------- fused f32 -> bf16 convert (8 segments, one launch) ----------------
struct CvtSeg { const float* s; unsigned short* d; int n4; };
struct CvtArgs { CvtSeg seg[8]; int blk_end[8]; };
__global__ __launch_bounds__(256) void f2b_multi_k(CvtArgs a){
  const int b = blockIdx.x;
  int si = 0;
  #pragma unroll
  for (int i=0;i<8;i++) if (b >= a.blk_end[i]) si = i+1;
  const int base = si ? a.blk_end[si-1] : 0;
  const int i4 = (b - base)*256 + threadIdx.x;
  if (i4 >= a.seg[si].n4) return;
  float4 f = ((const float4*)a.seg[si].s)[i4];
  union { unsigned short u[4]; uint2 v; } t;
  t.u[0]=f2bf(f.x); t.u[1]=f2bf(f.y); t.u[2]=f2bf(f.z); t.u[3]=f2bf(f.w);
  ((uint2*)a.seg[si].d)[i4] = t.v;
}

// ---------------- 256x256 8-wave pipelined GEMM (depth-3, counted vmcnt) ----
// FLAGS: 1=relu (EPI=0 only).
// EPI: 0 = bias(+relu)+bf16 store to Cb.
//      1 = QKV scatter: Q region (cols<nq, *qscale, len Lq) -> qb;
//          K region (nq..nq+nk) -> kb; V region -> transpose -> vtb.
// Requires M,N % 256 == 0, K % 32 == 0, K >= 128.
template<int FLAGS, int EPI>
__global__ __launch_bounds__(512, 2) void gemm8_k(
    const unsigned short* __restrict__ A, int lda,
    const unsigned short* __restrict__ B, int ldb,
    const float* __restrict__ bias,
    unsigned short* __restrict__ Cb,
    unsigned short* __restrict__ qb, unsigned short* __restrict__ kb,
    unsigned short* __restrict__ vtb,
    int M, int N, int K,
    int nq, int nk, int Lq, int Lkv, float qscale)
{
  __shared__ unsigned short smem[2][4][256*32];   // [A/B][slot][tile] = 128 KB
  const int tid  = threadIdx.x;
  const int wave = tid>>6, lane = tid&63;
  const int l15 = lane&15, l4 = lane>>4;

  int bid = blockIdx.x;
  if ((gridDim.x & 7) == 0){ const int cpx = gridDim.x>>3; bid = (bid&7)*cpx + (bid>>3); }
  const int nbm = M>>8;
  const int bm = bid % nbm, bn = bid / nbm;
  const int brow = bm<<8, bcol = bn<<8;
  const int wm0 = (wave>>2)*128, wn = (wave&3)*64;
  const int NT  = K>>5;

  // staging map: thread instr i covers LDS chunk l = i*512 + wave*64 + lane
  // (dest = wave-uniform base + lane*16B); global source is pre-swizzled.
  int ldsl[2]; const unsigned short* pA[2]; const unsigned short* pB[2];
  #pragma unroll
  for (int i=0;i<2;i++){
    const int l = i*512 + wave*64 + lane;
    const int grp = l>>3, sl = (l&7) ^ (grp&7);
    const int row = (grp<<1)|(sl>>2), c = sl&3;
    ldsl[i] = l<<3;                                  // element offset
    pA[i] = A + (size_t)(brow + row)*lda + (c<<3);
    pB[i] = B + (size_t)(bcol + row)*ldb + (c<<3);
  }

  f32x4 acc[8][4] = {};

  auto stageA = [&](int t){
    unsigned short* s = smem[0][t&3];
    #pragma unroll
    for (int i=0;i<2;i++) gload16(&s[ldsl[i]], pA[i] + t*32);
  };
  auto stageB = [&](int t){
    unsigned short* s = smem[1][t&3];
    #pragma unroll
    for (int i=0;i<2;i++) gload16(&s[ldsl[i]], pB[i] + t*32);
  };

  // prologue: tiles 0,1,2 in flight (12 loads); vmcnt(8) lands tile 0.
  stageA(0); stageB(0); stageA(1); stageB(1); stageA(2); stageB(2);
  asm volatile("s_waitcnt vmcnt(8)" ::: "memory");
  __builtin_amdgcn_s_barrier();

  // invariant at top of iter t: tile t landed; t+1,t+2 in flight (8 loads).
  for (int t=0; t<NT; ++t){
    const unsigned short* as = smem[0][t&3];
    const unsigned short* bs = smem[1][t&3];
    const bool pre = (t+3 < NT);

    // ---- phase a: stage A(t+3) || read B + A-lo || MFMA lo-quadrants ----
    if (pre) stageA(t+3);
    bf16x8 bf[4], af[4];
    #pragma unroll
    for (int n=0;n<4;n++) bf[n] = *(const bf16x8*)&bs[loff(wn + n*16 + l15, l4)];
    #pragma unroll
    for (int m=0;m<4;m++) af[m] = *(const bf16x8*)&as[loff(wm0 + m*16 + l15, l4)];
    __builtin_amdgcn_s_barrier();
    __builtin_amdgcn_s_setprio(1);
    #pragma unroll
    for (int m=0;m<4;m++)
      #pragma unroll
      for (int n=0;n<4;n++)
        acc[m][n] = __builtin_amdgcn_mfma_f32_16x16x32_bf16(af[m], bf[n], acc[m][n], 0,0,0);
    __builtin_amdgcn_s_setprio(0);
    __builtin_amdgcn_s_barrier();

    // ---- phase b: stage B(t+3) || read A-hi || MFMA hi-quadrants ----
    if (pre) stageB(t+3);
    #pragma unroll
    for (int m=0;m<4;m++) af[m] = *(const bf16x8*)&as[loff(wm0 + 64 + m*16 + l15, l4)];
    __builtin_amdgcn_s_barrier();
    __builtin_amdgcn_s_setprio(1);
    #pragma unroll
    for (int m=0;m<4;m++)
      #pragma unroll
      for (int n=0;n<4;n++)
        acc[4+m][n] = __builtin_amdgcn_mfma_f32_16x16x32_bf16(af[m], bf[n], acc[4+m][n], 0,0,0);
    __builtin_amdgcn_s_setprio(0);
    if (pre)            asm volatile("s_waitcnt vmcnt(8)" ::: "memory");  // tile t+1 landed
    else if (t+2 < NT)  asm volatile("s_waitcnt vmcnt(4)" ::: "memory");  // tile t+1 landed (tail)
    else                asm volatile("s_waitcnt vmcnt(0)" ::: "memory");  // final drain
    __builtin_amdgcn_s_barrier();
  }

  if constexpr (EPI == 0){
    // C/D layout: col = lane&15, row = (lane>>4)*4 + r
    #pragma unroll
    for (int mi=0;mi<8;mi++){
      #pragma unroll
      for (int r=0;r<4;r++){
        const int rr = brow + wm0 + mi*16 + l4*4 + r;
        #pragma unroll
        for (int n=0;n<4;n++){
          const int cc = bcol + wn + n*16 + l15;
          float v = acc[mi][n][r] + bias[cc];
          if (FLAGS & 1) v = fmaxf(v, 0.f);
          Cb[(size_t)rr*N + cc] = f2bf(v);
        }
      }
    }
  } else {
    const int voff = nq + nk;
    if (bcol < voff){
      // ---- Q/K-region: scatter to {qb|kb}[((nn*H+h)*L + t)*HD + d] ----
      const bool isq = (bcol < nq);
      unsigned short* dst = isq ? qb : kb;
      const int  base  = isq ? 0 : nq;
      const int  L     = isq ? Lq : Lkv;
      const float scale = isq ? qscale : 1.0f;
      #pragma unroll
      for (int mi=0;mi<8;mi++){
        #pragma unroll
        for (int r=0;r<4;r++){
          const int rr = brow + wm0 + mi*16 + l4*4 + r;
          const int t = rr>>2, nn = rr&3;
          #pragma unroll
          for (int n=0;n<4;n++){
            const int cc = bcol + wn + n*16 + l15;
            const int e = cc - base, h = e>>6, d = e&63;
            dst[((size_t)(nn*H_ + h)*L + t)*HD_ + d] = f2bf((acc[mi][n][r] + bias[cc])*scale);
          }
        }
      }
    } else {
      // ---- V-region: transpose through LDS, then 16B chunk writes ----
      unsigned short* cT = &smem[0][0][0];   // 65536 elems = whole 128 KB
      #pragma unroll
      for (int mi=0;mi<8;mi++){
        const int tl = (wm0>>2) + mi*4 + l4;   // token-local 0..63
        #pragma unroll
        for (int n=0;n<4;n++){
          const int ccl = wn + n*16 + l15;
          const float bi = bias[bcol + ccl];
          #pragma unroll
          for (int r=0;r<4;r++){               // r == batch index nn
            const int unit = r*8 + (tl>>3);
            cT[ccl*256 + ((unit ^ (ccl&7))<<3) + (tl&7)] = f2bf(acc[mi][n][r] + bi);
          }
        }
      }
      __syncthreads();
      const int t0 = brow>>2;
      #pragma unroll
      for (int i=0;i<16;i++){
        const int ch = i*512 + tid;
        const int tl8 = ch&7, nn = (ch>>3)&3, ccl = ch>>5;
        const int e = bcol - voff + ccl, h = e>>6, d = e&63;
        const int unit = (nn<<3) | tl8;
        const uint4 v = *(const uint4*)&cT[ccl*256 + ((unit ^ (ccl&7))<<3)];
        *(uint4*)(vtb + ((size_t)(nn*H_ + h)*HD_ + d)*Lkv + t0 + tl8*8) = v;
      }
    }
  }
}

// -------- split-K x2 GEMM (grid.z in {0,1}); z=0: +bias+res -> P0, z=1: raw -> P1 ----
// R14: double-buffered LDS + prefetch t+1 + counted vmcnt(6) + raw barriers
//      (R8-proven retrofit; accumulation order unchanged).
template<int BN>
__global__ __launch_bounds__(256) void gemm_splitk_k(
    const unsigned short* __restrict__ A, int lda,
    const unsigned short* __restrict__ B, int ldb,
    const float* __restrict__ bias,
    const float* __restrict__ res,
    float* __restrict__ P0, float* __restrict__ P1,
    int M, int N, int K)
{
  constexpr int NW = BN/32;
  constexpr int NLD = 4 + BN/32;            // gload16 per thread per tile
  __shared__ unsigned short a_sh[2][128*64];
  __shared__ unsigned short b_sh[2][BN*64];
  const int tid  = threadIdx.x;
  const int wave = tid>>6;
  const int lane = tid&63;
  const int l15 = lane&15, l4 = lane>>4;
  const int row0 = blockIdx.x*128, col0 = blockIdx.y*BN;
  const int wm = (wave>>1)*64, wn = (wave&1)*(BN/2);
  const int z = blockIdx.z;
  const int kh = K>>1;
  const int kbeg = z*kh;
  const int NT = kh>>6;                     // BK = 64

  const int lrow = tid>>3;
  const int scol = ((tid&7) ^ (lrow&7)) << 3;
  const int dst8 = (tid&7) << 3;

  auto stage = [&](int t){
    const unsigned short* ga = A + (size_t)(row0+lrow)*lda + kbeg + t*64 + scol;
    const unsigned short* gb = B + (size_t)(col0+lrow)*ldb + kbeg + t*64 + scol;
    unsigned short* as = a_sh[t&1];
    unsigned short* bs = b_sh[t&1];
    #pragma unroll
    for (int i=0;i<4;i++)
      gload16(&as[(lrow + i*32)*64 + dst8], ga + (size_t)(i*32)*lda);
    #pragma unroll
    for (int i=0;i<BN/32;i++)
      gload16(&bs[(lrow + i*32)*64 + dst8], gb + (size_t)(i*32)*ldb);
  };

  f32x4 acc[4][NW] = {};

  stage(0);
  for (int t=0; t<NT; ++t){
    if (t+1 < NT){
      stage(t+1);                                    // slot (t+1)&1, freed by prev-iter barrier
      asm volatile("s_waitcnt vmcnt(" "6" ")" ::: "memory");   // drain tile t (oldest NLD=6)
    } else {
      asm volatile("s_waitcnt vmcnt(0)" ::: "memory");
    }
    __builtin_amdgcn_s_barrier();

    const unsigned short* as = a_sh[t&1];
    const unsigned short* bs = b_sh[t&1];
    __builtin_amdgcn_s_setprio(1);
    #pragma unroll
    for (int kk=0;kk<2;kk++){
      const int sw = (((kk<<2)|l4) ^ (l15&7)) << 3;
      bf16x8 af[4], bfr[NW];
      #pragma unroll
      for (int m=0;m<4;m++)  af[m]  = *(const bf16x8*)&as[(wm + m*16 + l15)*64 + sw];
      #pragma unroll
      for (int n=0;n<NW;n++) bfr[n] = *(const bf16x8*)&bs[(wn + n*16 + l15)*64 + sw];
      #pragma unroll
      for (int m=0;m<4;m++)
        #pragma unroll
        for (int n=0;n<NW;n++)
          acc[m][n] = __builtin_amdgcn_mfma_f32_16x16x32_bf16(af[m], bfr[n], acc[m][n], 0,0,0);
    }
    __builtin_amdgcn_s_setprio(0);
    __builtin_amdgcn_s_barrier();
  }
  static_assert(NLD == 6 || BN != 64, "vmcnt literal assumes BN=64");

  float* out = z ? P1 : P0;
  #pragma unroll
  for (int m=0;m<4;m++){
    #pragma unroll
    for (int r=0;r<4;r++){
      const int rr = row0 + wm + m*16 + l4*4 + r;
      #pragma unroll
      for (int n=0;n<NW;n++){
        const int cc = col0 + wn + n*16 + l15;
        float v = acc[m][n][r];
        if (!z) v += bias[cc] + res[(size_t)rr*N + cc];
        out[(size_t)rr*N + cc] = v;
      }
    }
  }
}

// -------- QKV-projection GEMM with fused scatter epilogue (CA-Q only now) --------
template<int BN>
__global__ __launch_bounds__(256) void gemm_scat_k(
    const unsigned short* __restrict__ A, int lda,
    const unsigned short* __restrict__ B, int ldb,
    const float* __restrict__ bias,
    unsigned short* __restrict__ qb, unsigned short* __restrict__ kb,
    unsigned short* __restrict__ vtb,
    int M, int N, int K, int nq, int nk, int Lq, int Lkv, float qscale)
{
  constexpr int NW = BN/32;
  constexpr int SMEM_ELEMS = (BN==128) ? (128*132) : (128*64 + BN*64);
  __shared__ unsigned short smem[SMEM_ELEMS];
  unsigned short* a_sh = smem;
  unsigned short* b_sh = smem + 128*64;
  const int tid  = threadIdx.x;
  const int wave = tid>>6, lane = tid&63;
  const int l15 = lane&15, l4 = lane>>4;
  const int row0 = blockIdx.x*128, col0 = blockIdx.y*BN;
  const int wm = (wave>>1)*64, wn = (wave&1)*(BN/2);

  const int lrow = tid>>3;
  const int scol = ((tid&7) ^ (lrow&7)) << 3;
  const int dst8 = (tid&7) << 3;

  f32x4 acc[4][NW] = {};

  for (int k0=0; k0<K; k0+=64){
    const unsigned short* ga = A + (size_t)(row0+lrow)*lda + k0 + scol;
    const unsigned short* gb = B + (size_t)(col0+lrow)*ldb + k0 + scol;
    #pragma unroll
    for (int i=0;i<4;i++)
      gload16(&a_sh[(lrow + i*32)*64 + dst8], ga + (size_t)(i*32)*lda);
    #pragma unroll
    for (int i=0;i<BN/32;i++)
      gload16(&b_sh[(lrow + i*32)*64 + dst8], gb + (size_t)(i*32)*ldb);
    __syncthreads();
    #pragma unroll
    for (int kk=0;kk<2;kk++){
      const int sw = (((kk<<2)|l4) ^ (l15&7)) << 3;
      bf16x8 af[4], bfr[NW];
      #pragma unroll
      for (int m=0;m<4;m++)  af[m]  = *(const bf16x8*)&a_sh[(wm + m*16 + l15)*64 + sw];
      #pragma unroll
      for (int n=0;n<NW;n++) bfr[n] = *(const bf16x8*)&b_sh[(wn + n*16 + l15)*64 + sw];
      #pragma unroll
      for (int m=0;m<4;m++)
        #pragma unroll
        for (int n=0;n<NW;n++)
          acc[m][n] = __builtin_amdgcn_mfma_f32_16x16x32_bf16(af[m], bfr[n], acc[m][n], 0,0,0);
    }
    __syncthreads();
  }

  if (col0 < nq + nk){
    const bool isq = (col0 < nq);
    unsigned short* dst = isq ? qb : kb;
    const int  base  = isq ? 0 : nq;
    const int  L     = isq ? Lq : Lkv;
    const float scale = isq ? qscale : 1.0f;
    #pragma unroll
    for (int m=0;m<4;m++){
      #pragma unroll
      for (int r=0;r<4;r++){
        const int rr = row0 + wm + m*16 + l4*4 + r;
        const int t = rr>>2, nn = rr&3;
        #pragma unroll
        for (int n=0;n<NW;n++){
          const int cc = col0 + wn + n*16 + l15;
          const int e = cc - base, h = e>>6, d = e&63;
          const float v = (acc[m][n][r] + bias[cc]) * scale;
          dst[((size_t)(nn*H_ + h)*L + t)*HD_ + d] = f2bf(v);
        }
      }
    }
  }
}

// ---------------- flash attention, 32x32 swapped-QK^T, max-free softmax ----
// R9: pipelined  QK(i) -> PV(i-1) -> softmax(i); pa double-buffered; skewed
//     K/V staging with counted vmcnt(4).
template<bool PARTIAL, int NT>
__global__ __launch_bounds__(256,3) void attn_k(
    const unsigned short* __restrict__ qb, const unsigned short* __restrict__ kb,
    const unsigned short* __restrict__ vtb,
    unsigned short* __restrict__ o_out, float* __restrict__ l_out,
    int T, int S)
{
  static_assert((NT & 1) == 0 && NT >= 4, "NT even");
  __shared__ unsigned short k_sh[2][64*64];   // [slot][key][d] swizzled
  __shared__ unsigned short v_sh[2][64*64];   // [slot][d][key] swizzled (V^T)
  __shared__ float bc_sh[4][32];              // per-wave per-qrow broadcast (final mode)
  const int tid  = threadIdx.x;
  const int wave = tid>>6, lane = tid&63;
  const int l31  = lane&31;
  const int hv   = lane>>5;                // lane half
  const int bh   = blockIdx.x;             // batch-head
  const int z    = blockIdx.z;
  const int s_begin = z * (NT*64);
  const int q0   = blockIdx.y*128 + wave*32;
  const size_t qbase = (size_t)bh*T*HD_;
  const size_t kbase = (size_t)bh*S*HD_;
  const size_t vbase = (size_t)bh*HD_*S;

  const int strow = tid>>3;                // 0..31
  const int stch  = tid&7;
  const int sc_sw = (stch ^ (strow&7)) << 3;  // (row&7)==((row+32)&7) -> same swizzle
  const int dst8  = stch<<3;
  const unsigned short* gk0 = kb  + kbase + (size_t)s_begin*HD_;
  const unsigned short* gv0 = vtb + vbase + s_begin;

  auto stageK = [&](int t, int slot){
    const unsigned short* g = gk0 + (size_t)(t*64)*HD_;
    gload16(&k_sh[slot][(strow   )*64 + dst8], g + (size_t)(strow   )*HD_ + sc_sw);
    gload16(&k_sh[slot][(strow+32)*64 + dst8], g + (size_t)(strow+32)*HD_ + sc_sw);
  };
  auto stageV = [&](int t, int slot){
    const unsigned short* g = gv0 + t*64;
    gload16(&v_sh[slot][(strow   )*64 + dst8], g + (size_t)(strow   )*S + sc_sw);
    gload16(&v_sh[slot][(strow+32)*64 + dst8], g + (size_t)(strow+32)*S + sc_sw);
  };

  // ---- Q fragments first (fixed position in the vmcnt stream) ----
  bf16x8 qf[4];
  #pragma unroll
  for (int p=0;p<4;p++)
    qf[p] = *(const bf16x8*)(qb + qbase + (size_t)(q0 + l31)*HD_ + p*16 + hv*8);
  asm volatile("" ::: "memory");   // pin Q loads before staging in issue order

  // ---- prologue: K(0) ----
  stageK(0, 0);

  f32x16 o0 = {}, o1 = {};
  float rsa = 0.f, rsb = 0.f;
  bf16x8 paA[4], paB[4];

  auto QK = [&](const unsigned short* ksh, f32x16& s0, f32x16& s1){
    #pragma unroll
    for (int p=0;p<4;p++){
      const int slot = 2*p + hv;
      bf16x8 kf0 = *(const bf16x8*)&ksh[(l31     )*64 + ((slot ^ (l31&7))<<3)];
      bf16x8 kf1 = *(const bf16x8*)&ksh[(l31 + 32)*64 + ((slot ^ (l31&7))<<3)];
      s0 = __builtin_amdgcn_mfma_f32_32x32x16_bf16(kf0, qf[p], s0, 0,0,0);
      s1 = __builtin_amdgcn_mfma_f32_32x32x16_bf16(kf1, qf[p], s1, 0,0,0);
    }
  };
  auto PV = [&](const unsigned short* vsh, const bf16x8* pa){
    #pragma unroll
    for (int ks=0;ks<4;ks++){
      const int slot = 2*ks + hv;
      bf16x8 vf0 = *(const bf16x8*)&vsh[(l31     )*64 + ((slot ^ (l31&7))<<3)];
      bf16x8 vf1 = *(const bf16x8*)&vsh[(l31 + 32)*64 + ((slot ^ (l31&7))<<3)];
      o0 = __builtin_amdgcn_mfma_f32_32x32x16_bf16(pa[ks], vf0, o0, 0,0,0);
      o1 = __builtin_amdgcn_mfma_f32_32x32x16_bf16(pa[ks], vf1, o1, 0,0,0);
    }
  };
  auto SM = [&](f32x16& s0, f32x16& s1, bf16x8* pa){
    #pragma unroll
    for (int r=0;r<16;r++){
      s0[r] = __builtin_amdgcn_exp2f(s0[r]);
      s1[r] = __builtin_amdgcn_exp2f(s1[r]);
    }
    #pragma unroll
    for (int r=0;r<16;r+=2){
      rsa += s0[r]   + s1[r];
      rsb += s0[r+1] + s1[r+1];
    }
    #pragma unroll
    for (int ks=0;ks<4;ks++){
      const int base = 8*(ks&1);
      unsigned pkA0, pkA1, pkB0, pkB1;
      if (ks < 2){
        asm("v_cvt_pk_bf16_f32 %0, %1, %2" : "=v"(pkA0) : "v"(s0[base+0]), "v"(s0[base+1]));
        asm("v_cvt_pk_bf16_f32 %0, %1, %2" : "=v"(pkA1) : "v"(s0[base+2]), "v"(s0[base+3]));
        asm("v_cvt_pk_bf16_f32 %0, %1, %2" : "=v"(pkB0) : "v"(s0[base+4]), "v"(s0[base+5]));
        asm("v_cvt_pk_bf16_f32 %0, %1, %2" : "=v"(pkB1) : "v"(s0[base+6]), "v"(s0[base+7]));
      } else {
        asm("v_cvt_pk_bf16_f32 %0, %1, %2" : "=v"(pkA0) : "v"(s1[base+0]), "v"(s1[base+1]));
        asm("v_cvt_pk_bf16_f32 %0, %1, %2" : "=v"(pkA1) : "v"(s1[base+2]), "v"(s1[base+3]));
        asm("v_cvt_pk_bf16_f32 %0, %1, %2" : "=v"(pkB0) : "v"(s1[base+4]), "v"(s1[base+5]));
        asm("v_cvt_pk_bf16_f32 %0, %1, %2" : "=v"(pkB1) : "v"(s1[base+6]), "v"(s1[base+7]));
      }
      perm32swap(pkA0, pkB0);
      perm32swap(pkA1, pkB1);
      union { unsigned w[4]; bf16x8 v; } u;
      u.w[0] = pkA0; u.w[1] = pkA1; u.w[2] = pkB0; u.w[3] = pkB1;
      pa[ks] = u.v;
    }
  };

  // ---- iter 0 (peeled: no PV) ----
  {
    stageK(1, 1);
    stageV(0, 0);
    asm volatile("s_waitcnt vmcnt(4)" ::: "memory");   // drain K(0) + Q
    __builtin_amdgcn_s_barrier();
    f32x16 s0 = {}, s1 = {};
    __builtin_amdgcn_s_setprio(1);
    QK(k_sh[0], s0, s1);
    __builtin_amdgcn_s_setprio(0);
    SM(s0, s1, paA);
    __builtin_amdgcn_s_barrier();
  }

  auto BODY = [&](int i, const bf16x8* paPrev, bf16x8* paCur){
    const int kt = (i+1 < NT) ? (i+1) : (NT-1);       // clamped prefetch
    stageK(kt, (i+1)&1);
    stageV(i, i&1);
    asm volatile("s_waitcnt vmcnt(4)" ::: "memory");   // drain K(i), V(i-1)
    __builtin_amdgcn_s_barrier();
    f32x16 s0 = {}, s1 = {};
    __builtin_amdgcn_s_setprio(1);
    QK(k_sh[i&1], s0, s1);
    PV(v_sh[(i+1)&1], paPrev);                         // (i-1)&1 == (i+1)&1
    __builtin_amdgcn_s_setprio(0);
    SM(s0, s1, paCur);
    __builtin_amdgcn_s_barrier();
  };

  for (int ii=1; ii+1<NT; ii+=2){
    BODY(ii,   paA, paB);
    BODY(ii+1, paB, paA);
  }
  BODY(NT-1, paA, paB);

  // ---- epilogue: PV of last tile ----
  asm volatile("s_waitcnt vmcnt(0)" ::: "memory");
  __builtin_amdgcn_s_barrier();
  __builtin_amdgcn_s_setprio(1);
  PV(v_sh[(NT-1)&1], paB);
  __builtin_amdgcn_s_setprio(0);

  // ---- finalize l: one cross-half swap ----
  float l_run = rsa + rsb;
  {
    unsigned a_ = __builtin_bit_cast(unsigned, l_run), b_ = a_;
    perm32swap(a_, b_);
    l_run += __builtin_bit_cast(float, hv ? a_ : b_);
  }

  if constexpr (PARTIAL){
    const size_t obase = (size_t)(z*64 + bh)*T;
    #pragma unroll
    for (int r=0;r<16;r++){
      const int qr = (r&3) + 8*(r>>2) + 4*hv;
      unsigned short* op = o_out + (obase + q0 + qr)*HD_;
      op[l31]      = f2bf(o0[r]);
      op[l31 + 32] = f2bf(o1[r]);
    }
    if (hv == 0) l_out[obase + q0 + l31] = l_run;
  } else {
    bc_sh[wave][l31] = 1.f / l_run;
    const int nb = bh>>4, hh = bh&15;
    #pragma unroll
    for (int r=0;r<16;r++){
      const int qr  = (r&3) + 8*(r>>2) + 4*hv;
      const float inv = bc_sh[wave][qr];
      const int t = q0 + qr;
      unsigned short* op = o_out + ((size_t)t*NB_ + nb)*E_ + hh*HD_;
      op[l31]      = f2bf(o0[r]*inv);
      op[l31 + 32] = f2bf(o1[r]*inv);
    }
  }
}

// ---------------- combine split-KV partials ----------------
__global__ __launch_bounds__(256) void comb_k(
    const unsigned short* __restrict__ opart, const float* __restrict__ lpart,
    unsigned short* __restrict__ outb, int T)
{
  const int bh = blockIdx.y;
  const int t  = blockIdx.x*4 + (threadIdx.x>>6);
  const int d  = threadIdx.x&63;
  const size_t half = (size_t)64*T;
  const size_t row  = (size_t)bh*T + t;
  const float o = bf2f(opart[row*HD_ + d]) + bf2f(opart[(half + row)*HD_ + d]);
  const float l = lpart[row] + lpart[half + row];
  const int nb = bh>>4, hh = bh&15;
  outb[((size_t)t*NB_ + nb)*E_ + hh*HD_ + d] = f2bf(o / l);
}

// ---------------- LayerNorm over E=1024 of (p0+p1), one block per row ----------------
__global__ __launch_bounds__(256) void ln_k(
    const float* __restrict__ p0, const float* __restrict__ p1,
    const float* __restrict__ g, const float* __restrict__ bb,
    float* __restrict__ of, unsigned short* __restrict__ ob)
{
  const int row = blockIdx.x, tid = threadIdx.x;
  const size_t base = (size_t)row*E_;
  float v[4];
  #pragma unroll
  for (int i=0;i<4;i++){
    const int col = tid + 256*i;
    v[i] = p0[base + col] + p1[base + col];
  }
  float s  = v[0]+v[1]+v[2]+v[3];
  float s2 = v[0]*v[0]+v[1]*v[1]+v[2]*v[2]+v[3]*v[3];
  #pragma unroll
  for (int off=32; off>0; off>>=1){
    s  += __shfl_down(s, off);
    s2 += __shfl_down(s2, off);
  }
  __shared__ float red[8];
  if ((tid&63)==0){ red[tid>>6] = s; red[4+(tid>>6)] = s2; }
  __syncthreads();
  s  = red[0]+red[1]+red[2]+red[3];
  s2 = red[4]+red[5]+red[6]+red[7];
  const float mu   = s * (1.f/E_);
  const float var  = s2 * (1.f/E_) - mu*mu;
  const float rstd = rsqrtf(var + 1e-5f);
  #pragma unroll
  for (int i=0;i<4;i++){
    const int col = tid + 256*i;
    const float y = (v[i]-mu)*rstd*g[col] + bb[col];
    if (of) of[base + col] = y;
    if (ob) ob[base + col] = f2bf(y);
  }
}

// ---------------- driver ----------------
extern "C" void kernel_launch(void* const* d_in, const int* in_sizes, int n_in,
                              void* d_out, int out_size, void* d_ws, size_t ws_size,
                              hipStream_t stream)
{
  const float* tgt      = (const float*)d_in[0];
  const float* mem      = (const float*)d_in[1];
  const float* sa_w_in  = (const float*)d_in[2];
  const float* sa_b_in  = (const float*)d_in[3];
  const float* sa_w_out = (const float*)d_in[4];
  const float* sa_b_out = (const float*)d_in[5];
  const float* ca_w_in  = (const float*)d_in[6];
  const float* ca_b_in  = (const float*)d_in[7];
  const float* ca_w_out = (const float*)d_in[8];
  const float* ca_b_out = (const float*)d_in[9];
  const float* w1 = (const float*)d_in[10];
  const float* b1 = (const float*)d_in[11];
  const float* w2 = (const float*)d_in[12];
  const float* b2 = (const float*)d_in[13];
  const float* ln1_g=(const float*)d_in[14]; const float* ln1_b=(const float*)d_in[15];
  const float* ln2_g=(const float*)d_in[16]; const float* ln2_b=(const float*)d_in[17];
  const float* ln3_g=(const float*)d_in[18]; const float* ln3_b=(const float*)d_in[19];

  char* ws = (char*)d_ws;
  size_t off = 0;
  auto alloc = [&](size_t bytes)->char* {
    char* p = ws + off; off += (bytes + 255) & ~(size_t)255; return p;
  };
  unsigned short* w_sa_in_b  = (unsigned short*)alloc((size_t)3*E_*E_*2);
  unsigned short* w_sa_out_b = (unsigned short*)alloc((size_t)E_*E_*2);
  unsigned short* w_ca_in_b  = (unsigned short*)alloc((size_t)3*E_*E_*2);
  unsigned short* w_ca_out_b = (unsigned short*)alloc((size_t)E_*E_*2);
  unsigned short* w1_b  = (unsigned short*)alloc((size_t)FF_*E_*2);
  unsigned short* w2_b  = (unsigned short*)alloc((size_t)E_*FF_*2);
  unsigned short* tgt_b = (unsigned short*)alloc((size_t)M1_*E_*2);
  unsigned short* mem_b = (unsigned short*)alloc((size_t)M2_*E_*2);
  unsigned short* qbuf  = (unsigned short*)alloc((size_t)64*T_*HD_*2);
  unsigned short* kbuf  = (unsigned short*)alloc((size_t)64*S_*HD_*2);
  unsigned short* vtbuf = (unsigned short*)alloc((size_t)64*S_*HD_*2);
  unsigned short* cbuf  = (unsigned short*)alloc((size_t)M1_*FF_*2);
  unsigned short* atto  = (unsigned short*)alloc((size_t)M1_*E_*2);
  unsigned short* opart = (unsigned short*)alloc((size_t)2*64*T_*HD_*2);  // also reused as f32 P1 (16 MB)
  float*          lpart = (float*)alloc((size_t)2*64*T_*4);
  float* resf = (float*)alloc((size_t)M1_*E_*4);
  float* xf   = (float*)alloc((size_t)M1_*E_*4);
  unsigned short* xb = (unsigned short*)alloc((size_t)M1_*E_*2);
  (void)ws_size; (void)in_sizes; (void)n_in; (void)out_size;

  float* P1 = (float*)opart;   // 2*64*1024*64*2 B == M1_*E_*4 B exactly

  const float QSCALE = 0.125f * LOG2E;   // fold log2e into q so P = exp2(score)

  // ---- fused input/weight conversion (one launch) ----
  {
    CvtArgs a;
    const float* srcs[8] = {tgt, mem, sa_w_in, sa_w_out, ca_w_in, ca_w_out, w1, w2};
    unsigned short* dsts[8] = {tgt_b, mem_b, w_sa_in_b, w_sa_out_b, w_ca_in_b, w_ca_out_b, w1_b, w2_b};
    size_t ns[8] = {(size_t)M1_*E_, (size_t)M2_*E_, (size_t)3*E_*E_, (size_t)E_*E_,
                    (size_t)3*E_*E_, (size_t)E_*E_, (size_t)FF_*E_, (size_t)E_*FF_};
    int blk = 0;
    for (int i=0;i<8;i++){
      a.seg[i].s = srcs[i]; a.seg[i].d = dsts[i]; a.seg[i].n4 = (int)(ns[i]/4);
      blk += (a.seg[i].n4 + 255)/256;
      a.blk_end[i] = blk;
    }
    f2b_multi_k<<<blk, 256, 0, stream>>>(a);
  }

  // ---- self-attention block ----
  gemm8_k<0,1><<<(M1_/256)*((3*E_)/256), 512, 0, stream>>>(
      tgt_b, E_, w_sa_in_b, E_, sa_b_in, nullptr, qbuf, kbuf, vtbuf,
      M1_, 3*E_, E_, E_, E_, T_, T_, QSCALE);
  attn_k<false,16><<<dim3(64, T_/128, 1), 256, 0, stream>>>(
      qbuf, kbuf, vtbuf, atto, nullptr, T_, T_);
  gemm_splitk_k<64><<<dim3(M1_/128, E_/64, 2), 256, 0, stream>>>(
      atto, E_, w_sa_out_b, E_, sa_b_out, tgt, resf, P1, M1_, E_, E_);
  ln_k<<<M1_, 256, 0, stream>>>(resf, P1, ln1_g, ln1_b, xf, xb);

  // ---- cross-attention block ----
  gemm8_k<0,1><<<(M2_/256)*((2*E_)/256), 512, 0, stream>>>(
      mem_b, E_, w_ca_in_b + (size_t)E_*E_, E_, ca_b_in + E_, nullptr,
      nullptr, kbuf, vtbuf,
      M2_, 2*E_, E_, 0, E_, S_, S_, QSCALE);
  gemm_scat_k<64><<<dim3(M1_/128, E_/64), 256, 0, stream>>>(
      xb, E_, w_ca_in_b, E_, ca_b_in, qbuf, nullptr, nullptr,
      M1_, E_, E_, E_, 0, T_, S_, QSCALE);
  attn_k<true,16><<<dim3(64, T_/128, 2), 256, 0, stream>>>(
      qbuf, kbuf, vtbuf, opart, lpart, T_, S_);
  comb_k<<<dim3(T_/4, 64), 256, 0, stream>>>(opart, lpart, atto, T_);
  gemm_splitk_k<64><<<dim3(M1_/128, E_/64, 2), 256, 0, stream>>>(
      atto, E_, w_ca_out_b, E_, ca_b_out, xf, resf, P1, M1_, E_, E_);
  ln_k<<<M1_, 256, 0, stream>>>(resf, P1, ln2_g, ln2_b, xf, xb);

  // ---- FFN ----
  gemm8_k<5,0><<<(M1_/256)*(FF_/256), 512, 0, stream>>>(
      xb, E_, w1_b, E_, b1, cbuf, nullptr, nullptr, nullptr,
      M1_, FF_, E_, 0, 0, 0, 0, 0.f);
  gemm_splitk_k<64><<<dim3(M1_/128, E_/64, 2), 256, 0, stream>>>(
      cbuf, FF_, w2_b, FF_, b2, xf, resf, P1, M1_, E_, FF_);
  ln_k<<<M1_, 256, 0, stream>>>(resf, P1, ln3_g, ln3_b, (float*)d_out, nullptr);
}

// Round 8
// 369.940 us; speedup vs baseline: 1.0975x; 1.0280x over previous
//
#include <hip/hip_runtime.h>

// TransformerDecoderLayer forward, bf16-MFMA compute / fp32 accumulate.
// T=1024 S=2048 N=4 E=1024 H=16 HD=64 FF=4096.
// R15: restore measured-best config. gemm_splitk_k reverted to the R12/R13
//      2-barrier 24KB-LDS version (R14's 48KB dbuf retrofit cut residency
//      6->3 blocks/CU and regressed 49.5->63us: TLP was the hiding
//      mechanism, not pipelining). gemm8 depth-3 (FFN1 EPI=0, SA-QKV/CA-KV
//      EPI=1 with uint4 V-fix), attn_k R9, 2-partial ln_k all kept.

typedef __bf16 bf16x8 __attribute__((ext_vector_type(8)));
typedef float  f32x4  __attribute__((ext_vector_type(4)));
typedef float  f32x16 __attribute__((ext_vector_type(16)));

#define T_  1024
#define S_  2048
#define NB_ 4
#define E_  1024
#define H_  16
#define HD_ 64
#define FF_ 4096
#define M1_ (T_*NB_)   // 4096 tgt tokens
#define M2_ (S_*NB_)   // 8192 memory tokens
#define LOG2E 1.44269504088896f

__device__ __forceinline__ unsigned short f2bf(float f){
  unsigned int u = __builtin_bit_cast(unsigned int, f);
  u += 0x7fffu + ((u>>16)&1u);           // RNE
  return (unsigned short)(u>>16);
}
__device__ __forceinline__ float bf2f(unsigned short h){
  unsigned int u = ((unsigned int)h)<<16;
  return __builtin_bit_cast(float, u);
}

// async global->LDS, 16 B per lane. LDS dest must be wave-uniform base + lane*16.
__device__ __forceinline__ void gload16(unsigned short* l, const unsigned short* g){
  __builtin_amdgcn_global_load_lds(
      (const __attribute__((address_space(1))) unsigned int*)g,
      (__attribute__((address_space(3))) unsigned int*)l, 16, 0, 0);
}

// v_permlane32_swap_b32: a.hi32lanes <-> b.lo32lanes (both operands updated).
__device__ __forceinline__ void perm32swap(unsigned &a, unsigned &b){
  asm("v_permlane32_swap_b32 %0, %1" : "+v"(a), "+v"(b));
}

// LDS offset (elements) for a 256x32 bf16 tile stored as chunk-permuted
// row-pairs: group = row>>1 (128 B = one full bank sweep), slot-in-group =
// ((row&1)*4 | kchunk) ^ (group&7).  Bijective; frag reads land 2-way.
__device__ __forceinline__ int loff(int row, int kc){
  return ((row>>1)<<6) + (((((row&1)<<2)|kc) ^ ((row>>1)&7))<<3);
}

// ---------------- fused f32 -> bf16 convert (8 segments, one launch) ----------------
struct CvtSeg { const float* s; unsigned short* d; int n4; };
struct CvtArgs { CvtSeg seg[8]; int blk_end[8]; };
__global__ __launch_bounds__(256) void f2b_multi_k(CvtArgs a){
  const int b = blockIdx.x;
  int si = 0;
  #pragma unroll
  for (int i=0;i<8;i++) if (b >= a.blk_end[i]) si = i+1;
  const int base = si ? a.blk_end[si-1] : 0;
  const int i4 = (b - base)*256 + threadIdx.x;
  if (i4 >= a.seg[si].n4) return;
  float4 f = ((const float4*)a.seg[si].s)[i4];
  union { unsigned short u[4]; uint2 v; } t;
  t.u[0]=f2bf(f.x); t.u[1]=f2bf(f.y); t.u[2]=f2bf(f.z); t.u[3]=f2bf(f.w);
  ((uint2*)a.seg[si].d)[i4] = t.v;
}

// ---------------- 256x256 8-wave pipelined GEMM (depth-3, counted vmcnt) ----
// FLAGS: 1=relu (EPI=0 only).
// EPI: 0 = bias(+relu)+bf16 store to Cb.
//      1 = QKV scatter: Q region (cols<nq, *qscale, len Lq) -> qb;
//          K region (nq..nq+nk) -> kb; V region -> transpose -> vtb.
// Requires M,N % 256 == 0, K % 32 == 0, K >= 128.
template<int FLAGS, int EPI>
__global__ __launch_bounds__(512, 2) void gemm8_k(
    const unsigned short* __restrict__ A, int lda,
    const unsigned short* __restrict__ B, int ldb,
    const float* __restrict__ bias,
    unsigned short* __restrict__ Cb,
    unsigned short* __restrict__ qb, unsigned short* __restrict__ kb,
    unsigned short* __restrict__ vtb,
    int M, int N, int K,
    int nq, int nk, int Lq, int Lkv, float qscale)
{
  __shared__ unsigned short smem[2][4][256*32];   // [A/B][slot][tile] = 128 KB
  const int tid  = threadIdx.x;
  const int wave = tid>>6, lane = tid&63;
  const int l15 = lane&15, l4 = lane>>4;

  int bid = blockIdx.x;
  if ((gridDim.x & 7) == 0){ const int cpx = gridDim.x>>3; bid = (bid&7)*cpx + (bid>>3); }
  const int nbm = M>>8;
  const int bm = bid % nbm, bn = bid / nbm;
  const int brow = bm<<8, bcol = bn<<8;
  const int wm0 = (wave>>2)*128, wn = (wave&3)*64;
  const int NT  = K>>5;

  // staging map: thread instr i covers LDS chunk l = i*512 + wave*64 + lane
  // (dest = wave-uniform base + lane*16B); global source is pre-swizzled.
  int ldsl[2]; const unsigned short* pA[2]; const unsigned short* pB[2];
  #pragma unroll
  for (int i=0;i<2;i++){
    const int l = i*512 + wave*64 + lane;
    const int grp = l>>3, sl = (l&7) ^ (grp&7);
    const int row = (grp<<1)|(sl>>2), c = sl&3;
    ldsl[i] = l<<3;                                  // element offset
    pA[i] = A + (size_t)(brow + row)*lda + (c<<3);
    pB[i] = B + (size_t)(bcol + row)*ldb + (c<<3);
  }

  f32x4 acc[8][4] = {};

  auto stageA = [&](int t){
    unsigned short* s = smem[0][t&3];
    #pragma unroll
    for (int i=0;i<2;i++) gload16(&s[ldsl[i]], pA[i] + t*32);
  };
  auto stageB = [&](int t){
    unsigned short* s = smem[1][t&3];
    #pragma unroll
    for (int i=0;i<2;i++) gload16(&s[ldsl[i]], pB[i] + t*32);
  };

  // prologue: tiles 0,1,2 in flight (12 loads); vmcnt(8) lands tile 0.
  stageA(0); stageB(0); stageA(1); stageB(1); stageA(2); stageB(2);
  asm volatile("s_waitcnt vmcnt(8)" ::: "memory");
  __builtin_amdgcn_s_barrier();

  // invariant at top of iter t: tile t landed; t+1,t+2 in flight (8 loads).
  for (int t=0; t<NT; ++t){
    const unsigned short* as = smem[0][t&3];
    const unsigned short* bs = smem[1][t&3];
    const bool pre = (t+3 < NT);

    // ---- phase a: stage A(t+3) || read B + A-lo || MFMA lo-quadrants ----
    if (pre) stageA(t+3);
    bf16x8 bf[4], af[4];
    #pragma unroll
    for (int n=0;n<4;n++) bf[n] = *(const bf16x8*)&bs[loff(wn + n*16 + l15, l4)];
    #pragma unroll
    for (int m=0;m<4;m++) af[m] = *(const bf16x8*)&as[loff(wm0 + m*16 + l15, l4)];
    __builtin_amdgcn_s_barrier();
    __builtin_amdgcn_s_setprio(1);
    #pragma unroll
    for (int m=0;m<4;m++)
      #pragma unroll
      for (int n=0;n<4;n++)
        acc[m][n] = __builtin_amdgcn_mfma_f32_16x16x32_bf16(af[m], bf[n], acc[m][n], 0,0,0);
    __builtin_amdgcn_s_setprio(0);
    __builtin_amdgcn_s_barrier();

    // ---- phase b: stage B(t+3) || read A-hi || MFMA hi-quadrants ----
    if (pre) stageB(t+3);
    #pragma unroll
    for (int m=0;m<4;m++) af[m] = *(const bf16x8*)&as[loff(wm0 + 64 + m*16 + l15, l4)];
    __builtin_amdgcn_s_barrier();
    __builtin_amdgcn_s_setprio(1);
    #pragma unroll
    for (int m=0;m<4;m++)
      #pragma unroll
      for (int n=0;n<4;n++)
        acc[4+m][n] = __builtin_amdgcn_mfma_f32_16x16x32_bf16(af[m], bf[n], acc[4+m][n], 0,0,0);
    __builtin_amdgcn_s_setprio(0);
    if (pre)            asm volatile("s_waitcnt vmcnt(8)" ::: "memory");  // tile t+1 landed
    else if (t+2 < NT)  asm volatile("s_waitcnt vmcnt(4)" ::: "memory");  // tile t+1 landed (tail)
    else                asm volatile("s_waitcnt vmcnt(0)" ::: "memory");  // final drain
    __builtin_amdgcn_s_barrier();
  }

  if constexpr (EPI == 0){
    // C/D layout: col = lane&15, row = (lane>>4)*4 + r
    #pragma unroll
    for (int mi=0;mi<8;mi++){
      #pragma unroll
      for (int r=0;r<4;r++){
        const int rr = brow + wm0 + mi*16 + l4*4 + r;
        #pragma unroll
        for (int n=0;n<4;n++){
          const int cc = bcol + wn + n*16 + l15;
          float v = acc[mi][n][r] + bias[cc];
          if (FLAGS & 1) v = fmaxf(v, 0.f);
          Cb[(size_t)rr*N + cc] = f2bf(v);
        }
      }
    }
  } else {
    const int voff = nq + nk;
    if (bcol < voff){
      // ---- Q/K-region: scatter to {qb|kb}[((nn*H+h)*L + t)*HD + d] ----
      const bool isq = (bcol < nq);
      unsigned short* dst = isq ? qb : kb;
      const int  base  = isq ? 0 : nq;
      const int  L     = isq ? Lq : Lkv;
      const float scale = isq ? qscale : 1.0f;
      #pragma unroll
      for (int mi=0;mi<8;mi++){
        #pragma unroll
        for (int r=0;r<4;r++){
          const int rr = brow + wm0 + mi*16 + l4*4 + r;
          const int t = rr>>2, nn = rr&3;
          #pragma unroll
          for (int n=0;n<4;n++){
            const int cc = bcol + wn + n*16 + l15;
            const int e = cc - base, h = e>>6, d = e&63;
            dst[((size_t)(nn*H_ + h)*L + t)*HD_ + d] = f2bf((acc[mi][n][r] + bias[cc])*scale);
          }
        }
      }
    } else {
      // ---- V-region: transpose through LDS, then 16B chunk writes ----
      unsigned short* cT = &smem[0][0][0];   // 65536 elems = whole 128 KB
      #pragma unroll
      for (int mi=0;mi<8;mi++){
        const int tl = (wm0>>2) + mi*4 + l4;   // token-local 0..63
        #pragma unroll
        for (int n=0;n<4;n++){
          const int ccl = wn + n*16 + l15;
          const float bi = bias[bcol + ccl];
          #pragma unroll
          for (int r=0;r<4;r++){               // r == batch index nn
            const int unit = r*8 + (tl>>3);
            cT[ccl*256 + ((unit ^ (ccl&7))<<3) + (tl&7)] = f2bf(acc[mi][n][r] + bi);
          }
        }
      }
      __syncthreads();
      const int t0 = brow>>2;
      #pragma unroll
      for (int i=0;i<16;i++){
        const int ch = i*512 + tid;
        const int tl8 = ch&7, nn = (ch>>3)&3, ccl = ch>>5;
        const int e = bcol - voff + ccl, h = e>>6, d = e&63;
        const int unit = (nn<<3) | tl8;
        const uint4 v = *(const uint4*)&cT[ccl*256 + ((unit ^ (ccl&7))<<3)];
        *(uint4*)(vtb + ((size_t)(nn*H_ + h)*HD_ + d)*Lkv + t0 + tl8*8) = v;
      }
    }
  }
}

// -------- split-K x2 GEMM (grid.z in {0,1}); z=0: +bias+res -> P0, z=1: raw -> P1 ----
// R15: reverted to the R12/R13 2-barrier 24KB-LDS version (6 blocks/CU TLP).
template<int BN>
__global__ __launch_bounds__(256) void gemm_splitk_k(
    const unsigned short* __restrict__ A, int lda,
    const unsigned short* __restrict__ B, int ldb,
    const float* __restrict__ bias,
    const float* __restrict__ res,
    float* __restrict__ P0, float* __restrict__ P1,
    int M, int N, int K)
{
  constexpr int NW = BN/32;
  __shared__ unsigned short a_sh[128*64];
  __shared__ unsigned short b_sh[BN*64];
  const int tid  = threadIdx.x;
  const int wave = tid>>6;
  const int lane = tid&63;
  const int l15 = lane&15, l4 = lane>>4;
  const int row0 = blockIdx.x*128, col0 = blockIdx.y*BN;
  const int wm = (wave>>1)*64, wn = (wave&1)*(BN/2);
  const int z = blockIdx.z;
  const int kh = K>>1;
  const int kbeg = z*kh;

  const int lrow = tid>>3;
  const int scol = ((tid&7) ^ (lrow&7)) << 3;
  const int dst8 = (tid&7) << 3;

  f32x4 acc[4][NW] = {};

  for (int k0=kbeg; k0<kbeg+kh; k0+=64){
    const unsigned short* ga = A + (size_t)(row0+lrow)*lda + k0 + scol;
    const unsigned short* gb = B + (size_t)(col0+lrow)*ldb + k0 + scol;
    #pragma unroll
    for (int i=0;i<4;i++)
      gload16(&a_sh[(lrow + i*32)*64 + dst8], ga + (size_t)(i*32)*lda);
    #pragma unroll
    for (int i=0;i<BN/32;i++)
      gload16(&b_sh[(lrow + i*32)*64 + dst8], gb + (size_t)(i*32)*ldb);
    __syncthreads();
    #pragma unroll
    for (int kk=0;kk<2;kk++){
      const int sw = (((kk<<2)|l4) ^ (l15&7)) << 3;
      bf16x8 af[4], bfr[NW];
      #pragma unroll
      for (int m=0;m<4;m++)  af[m]  = *(const bf16x8*)&a_sh[(wm + m*16 + l15)*64 + sw];
      #pragma unroll
      for (int n=0;n<NW;n++) bfr[n] = *(const bf16x8*)&b_sh[(wn + n*16 + l15)*64 + sw];
      #pragma unroll
      for (int m=0;m<4;m++)
        #pragma unroll
        for (int n=0;n<NW;n++)
          acc[m][n] = __builtin_amdgcn_mfma_f32_16x16x32_bf16(af[m], bfr[n], acc[m][n], 0,0,0);
    }
    __syncthreads();
  }

  float* out = z ? P1 : P0;
  #pragma unroll
  for (int m=0;m<4;m++){
    #pragma unroll
    for (int r=0;r<4;r++){
      const int rr = row0 + wm + m*16 + l4*4 + r;
      #pragma unroll
      for (int n=0;n<NW;n++){
        const int cc = col0 + wn + n*16 + l15;
        float v = acc[m][n][r];
        if (!z) v += bias[cc] + res[(size_t)rr*N + cc];
        out[(size_t)rr*N + cc] = v;
      }
    }
  }
}

// -------- QKV-projection GEMM with fused scatter epilogue (CA-Q only now) --------
template<int BN>
__global__ __launch_bounds__(256) void gemm_scat_k(
    const unsigned short* __restrict__ A, int lda,
    const unsigned short* __restrict__ B, int ldb,
    const float* __restrict__ bias,
    unsigned short* __restrict__ qb, unsigned short* __restrict__ kb,
    unsigned short* __restrict__ vtb,
    int M, int N, int K, int nq, int nk, int Lq, int Lkv, float qscale)
{
  constexpr int NW = BN/32;
  __shared__ unsigned short a_sh[128*64];
  __shared__ unsigned short b_sh[BN*64];
  const int tid  = threadIdx.x;
  const int wave = tid>>6, lane = tid&63;
  const int l15 = lane&15, l4 = lane>>4;
  const int row0 = blockIdx.x*128, col0 = blockIdx.y*BN;
  const int wm = (wave>>1)*64, wn = (wave&1)*(BN/2);

  const int lrow = tid>>3;
  const int scol = ((tid&7) ^ (lrow&7)) << 3;
  const int dst8 = (tid&7) << 3;

  f32x4 acc[4][NW] = {};

  for (int k0=0; k0<K; k0+=64){
    const unsigned short* ga = A + (size_t)(row0+lrow)*lda + k0 + scol;
    const unsigned short* gb = B + (size_t)(col0+lrow)*ldb + k0 + scol;
    #pragma unroll
    for (int i=0;i<4;i++)
      gload16(&a_sh[(lrow + i*32)*64 + dst8], ga + (size_t)(i*32)*lda);
    #pragma unroll
    for (int i=0;i<BN/32;i++)
      gload16(&b_sh[(lrow + i*32)*64 + dst8], gb + (size_t)(i*32)*ldb);
    __syncthreads();
    #pragma unroll
    for (int kk=0;kk<2;kk++){
      const int sw = (((kk<<2)|l4) ^ (l15&7)) << 3;
      bf16x8 af[4], bfr[NW];
      #pragma unroll
      for (int m=0;m<4;m++)  af[m]  = *(const bf16x8*)&a_sh[(wm + m*16 + l15)*64 + sw];
      #pragma unroll
      for (int n=0;n<NW;n++) bfr[n] = *(const bf16x8*)&b_sh[(wn + n*16 + l15)*64 + sw];
      #pragma unroll
      for (int m=0;m<4;m++)
        #pragma unroll
        for (int n=0;n<NW;n++)
          acc[m][n] = __builtin_amdgcn_mfma_f32_16x16x32_bf16(af[m], bfr[n], acc[m][n], 0,0,0);
    }
    __syncthreads();
  }

  if (col0 < nq + nk){
    const bool isq = (col0 < nq);
    unsigned short* dst = isq ? qb : kb;
    const int  base  = isq ? 0 : nq;
    const int  L     = isq ? Lq : Lkv;
    const float scale = isq ? qscale : 1.0f;
    #pragma unroll
    for (int m=0;m<4;m++){
      #pragma unroll
      for (int r=0;r<4;r++){
        const int rr = row0 + wm + m*16 + l4*4 + r;
        const int t = rr>>2, nn = rr&3;
        #pragma unroll
        for (int n=0;n<NW;n++){
          const int cc = col0 + wn + n*16 + l15;
          const int e = cc - base, h = e>>6, d = e&63;
          const float v = (acc[m][n][r] + bias[cc]) * scale;
          dst[((size_t)(nn*H_ + h)*L + t)*HD_ + d] = f2bf(v);
        }
      }
    }
  }
}

// ---------------- flash attention, 32x32 swapped-QK^T, max-free softmax ----
// R9: pipelined  QK(i) -> PV(i-1) -> softmax(i); pa double-buffered; skewed
//     K/V staging with counted vmcnt(4).
template<bool PARTIAL, int NT>
__global__ __launch_bounds__(256,3) void attn_k(
    const unsigned short* __restrict__ qb, const unsigned short* __restrict__ kb,
    const unsigned short* __restrict__ vtb,
    unsigned short* __restrict__ o_out, float* __restrict__ l_out,
    int T, int S)
{
  static_assert((NT & 1) == 0 && NT >= 4, "NT even");
  __shared__ unsigned short k_sh[2][64*64];   // [slot][key][d] swizzled
  __shared__ unsigned short v_sh[2][64*64];   // [slot][d][key] swizzled (V^T)
  __shared__ float bc_sh[4][32];              // per-wave per-qrow broadcast (final mode)
  const int tid  = threadIdx.x;
  const int wave = tid>>6, lane = tid&63;
  const int l31  = lane&31;
  const int hv   = lane>>5;                // lane half
  const int bh   = blockIdx.x;             // batch-head
  const int z    = blockIdx.z;
  const int s_begin = z * (NT*64);
  const int q0   = blockIdx.y*128 + wave*32;
  const size_t qbase = (size_t)bh*T*HD_;
  const size_t kbase = (size_t)bh*S*HD_;
  const size_t vbase = (size_t)bh*HD_*S;

  const int strow = tid>>3;                // 0..31
  const int stch  = tid&7;
  const int sc_sw = (stch ^ (strow&7)) << 3;  // (row&7)==((row+32)&7) -> same swizzle
  const int dst8  = stch<<3;
  const unsigned short* gk0 = kb  + kbase + (size_t)s_begin*HD_;
  const unsigned short* gv0 = vtb + vbase + s_begin;

  auto stageK = [&](int t, int slot){
    const unsigned short* g = gk0 + (size_t)(t*64)*HD_;
    gload16(&k_sh[slot][(strow   )*64 + dst8], g + (size_t)(strow   )*HD_ + sc_sw);
    gload16(&k_sh[slot][(strow+32)*64 + dst8], g + (size_t)(strow+32)*HD_ + sc_sw);
  };
  auto stageV = [&](int t, int slot){
    const unsigned short* g = gv0 + t*64;
    gload16(&v_sh[slot][(strow   )*64 + dst8], g + (size_t)(strow   )*S + sc_sw);
    gload16(&v_sh[slot][(strow+32)*64 + dst8], g + (size_t)(strow+32)*S + sc_sw);
  };

  // ---- Q fragments first (fixed position in the vmcnt stream) ----
  bf16x8 qf[4];
  #pragma unroll
  for (int p=0;p<4;p++)
    qf[p] = *(const bf16x8*)(qb + qbase + (size_t)(q0 + l31)*HD_ + p*16 + hv*8);
  asm volatile("" ::: "memory");   // pin Q loads before staging in issue order

  // ---- prologue: K(0) ----
  stageK(0, 0);

  f32x16 o0 = {}, o1 = {};
  float rsa = 0.f, rsb = 0.f;
  bf16x8 paA[4], paB[4];

  auto QK = [&](const unsigned short* ksh, f32x16& s0, f32x16& s1){
    #pragma unroll
    for (int p=0;p<4;p++){
      const int slot = 2*p + hv;
      bf16x8 kf0 = *(const bf16x8*)&ksh[(l31     )*64 + ((slot ^ (l31&7))<<3)];
      bf16x8 kf1 = *(const bf16x8*)&ksh[(l31 + 32)*64 + ((slot ^ (l31&7))<<3)];
      s0 = __builtin_amdgcn_mfma_f32_32x32x16_bf16(kf0, qf[p], s0, 0,0,0);
      s1 = __builtin_amdgcn_mfma_f32_32x32x16_bf16(kf1, qf[p], s1, 0,0,0);
    }
  };
  auto PV = [&](const unsigned short* vsh, const bf16x8* pa){
    #pragma unroll
    for (int ks=0;ks<4;ks++){
      const int slot = 2*ks + hv;
      bf16x8 vf0 = *(const bf16x8*)&vsh[(l31     )*64 + ((slot ^ (l31&7))<<3)];
      bf16x8 vf1 = *(const bf16x8*)&vsh[(l31 + 32)*64 + ((slot ^ (l31&7))<<3)];
      o0 = __builtin_amdgcn_mfma_f32_32x32x16_bf16(pa[ks], vf0, o0, 0,0,0);
      o1 = __builtin_amdgcn_mfma_f32_32x32x16_bf16(pa[ks], vf1, o1, 0,0,0);
    }
  };
  auto SM = [&](f32x16& s0, f32x16& s1, bf16x8* pa){
    #pragma unroll
    for (int r=0;r<16;r++){
      s0[r] = __builtin_amdgcn_exp2f(s0[r]);
      s1[r] = __builtin_amdgcn_exp2f(s1[r]);
    }
    #pragma unroll
    for (int r=0;r<16;r+=2){
      rsa += s0[r]   + s1[r];
      rsb += s0[r+1] + s1[r+1];
    }
    #pragma unroll
    for (int ks=0;ks<4;ks++){
      const int base = 8*(ks&1);
      unsigned pkA0, pkA1, pkB0, pkB1;
      if (ks < 2){
        asm("v_cvt_pk_bf16_f32 %0, %1, %2" : "=v"(pkA0) : "v"(s0[base+0]), "v"(s0[base+1]));
        asm("v_cvt_pk_bf16_f32 %0, %1, %2" : "=v"(pkA1) : "v"(s0[base+2]), "v"(s0[base+3]));
        asm("v_cvt_pk_bf16_f32 %0, %1, %2" : "=v"(pkB0) : "v"(s0[base+4]), "v"(s0[base+5]));
        asm("v_cvt_pk_bf16_f32 %0, %1, %2" : "=v"(pkB1) : "v"(s0[base+6]), "v"(s0[base+7]));
      } else {
        asm("v_cvt_pk_bf16_f32 %0, %1, %2" : "=v"(pkA0) : "v"(s1[base+0]), "v"(s1[base+1]));
        asm("v_cvt_pk_bf16_f32 %0, %1, %2" : "=v"(pkA1) : "v"(s1[base+2]), "v"(s1[base+3]));
        asm("v_cvt_pk_bf16_f32 %0, %1, %2" : "=v"(pkB0) : "v"(s1[base+4]), "v"(s1[base+5]));
        asm("v_cvt_pk_bf16_f32 %0, %1, %2" : "=v"(pkB1) : "v"(s1[base+6]), "v"(s1[base+7]));
      }
      perm32swap(pkA0, pkB0);
      perm32swap(pkA1, pkB1);
      union { unsigned w[4]; bf16x8 v; } u;
      u.w[0] = pkA0; u.w[1] = pkA1; u.w[2] = pkB0; u.w[3] = pkB1;
      pa[ks] = u.v;
    }
  };

  // ---- iter 0 (peeled: no PV) ----
  {
    stageK(1, 1);
    stageV(0, 0);
    asm volatile("s_waitcnt vmcnt(4)" ::: "memory");   // drain K(0) + Q
    __builtin_amdgcn_s_barrier();
    f32x16 s0 = {}, s1 = {};
    __builtin_amdgcn_s_setprio(1);
    QK(k_sh[0], s0, s1);
    __builtin_amdgcn_s_setprio(0);
    SM(s0, s1, paA);
    __builtin_amdgcn_s_barrier();
  }

  auto BODY = [&](int i, const bf16x8* paPrev, bf16x8* paCur){
    const int kt = (i+1 < NT) ? (i+1) : (NT-1);       // clamped prefetch
    stageK(kt, (i+1)&1);
    stageV(i, i&1);
    asm volatile("s_waitcnt vmcnt(4)" ::: "memory");   // drain K(i), V(i-1)
    __builtin_amdgcn_s_barrier();
    f32x16 s0 = {}, s1 = {};
    __builtin_amdgcn_s_setprio(1);
    QK(k_sh[i&1], s0, s1);
    PV(v_sh[(i+1)&1], paPrev);                         // (i-1)&1 == (i+1)&1
    __builtin_amdgcn_s_setprio(0);
    SM(s0, s1, paCur);
    __builtin_amdgcn_s_barrier();
  };

  for (int ii=1; ii+1<NT; ii+=2){
    BODY(ii,   paA, paB);
    BODY(ii+1, paB, paA);
  }
  BODY(NT-1, paA, paB);

  // ---- epilogue: PV of last tile ----
  asm volatile("s_waitcnt vmcnt(0)" ::: "memory");
  __builtin_amdgcn_s_barrier();
  __builtin_amdgcn_s_setprio(1);
  PV(v_sh[(NT-1)&1], paB);
  __builtin_amdgcn_s_setprio(0);

  // ---- finalize l: one cross-half swap ----
  float l_run = rsa + rsb;
  {
    unsigned a_ = __builtin_bit_cast(unsigned, l_run), b_ = a_;
    perm32swap(a_, b_);
    l_run += __builtin_bit_cast(float, hv ? a_ : b_);
  }

  if constexpr (PARTIAL){
    const size_t obase = (size_t)(z*64 + bh)*T;
    #pragma unroll
    for (int r=0;r<16;r++){
      const int qr = (r&3) + 8*(r>>2) + 4*hv;
      unsigned short* op = o_out + (obase + q0 + qr)*HD_;
      op[l31]      = f2bf(o0[r]);
      op[l31 + 32] = f2bf(o1[r]);
    }
    if (hv == 0) l_out[obase + q0 + l31] = l_run;
  } else {
    bc_sh[wave][l31] = 1.f / l_run;
    const int nb = bh>>4, hh = bh&15;
    #pragma unroll
    for (int r=0;r<16;r++){
      const int qr  = (r&3) + 8*(r>>2) + 4*hv;
      const float inv = bc_sh[wave][qr];
      const int t = q0 + qr;
      unsigned short* op = o_out + ((size_t)t*NB_ + nb)*E_ + hh*HD_;
      op[l31]      = f2bf(o0[r]*inv);
      op[l31 + 32] = f2bf(o1[r]*inv);
    }
  }
}

// ---------------- combine split-KV partials ----------------
__global__ __launch_bounds__(256) void comb_k(
    const unsigned short* __restrict__ opart, const float* __restrict__ lpart,
    unsigned short* __restrict__ outb, int T)
{
  const int bh = blockIdx.y;
  const int t  = blockIdx.x*4 + (threadIdx.x>>6);
  const int d  = threadIdx.x&63;
  const size_t half = (size_t)64*T;
  const size_t row  = (size_t)bh*T + t;
  const float o = bf2f(opart[row*HD_ + d]) + bf2f(opart[(half + row)*HD_ + d]);
  const float l = lpart[row] + lpart[half + row];
  const int nb = bh>>4, hh = bh&15;
  outb[((size_t)t*NB_ + nb)*E_ + hh*HD_ + d] = f2bf(o / l);
}

// ---------------- LayerNorm over E=1024 of (p0+p1), one block per row ----------------
__global__ __launch_bounds__(256) void ln_k(
    const float* __restrict__ p0, const float* __restrict__ p1,
    const float* __restrict__ g, const float* __restrict__ bb,
    float* __restrict__ of, unsigned short* __restrict__ ob)
{
  const int row = blockIdx.x, tid = threadIdx.x;
  const size_t base = (size_t)row*E_;
  float v[4];
  #pragma unroll
  for (int i=0;i<4;i++){
    const int col = tid + 256*i;
    v[i] = p0[base + col] + p1[base + col];
  }
  float s  = v[0]+v[1]+v[2]+v[3];
  float s2 = v[0]*v[0]+v[1]*v[1]+v[2]*v[2]+v[3]*v[3];
  #pragma unroll
  for (int off=32; off>0; off>>=1){
    s  += __shfl_down(s, off);
    s2 += __shfl_down(s2, off);
  }
  __shared__ float red[8];
  if ((tid&63)==0){ red[tid>>6] = s; red[4+(tid>>6)] = s2; }
  __syncthreads();
  s  = red[0]+red[1]+red[2]+red[3];
  s2 = red[4]+red[5]+red[6]+red[7];
  const float mu   = s * (1.f/E_);
  const float var  = s2 * (1.f/E_) - mu*mu;
  const float rstd = rsqrtf(var + 1e-5f);
  #pragma unroll
  for (int i=0;i<4;i++){
    const int col = tid + 256*i;
    const float y = (v[i]-mu)*rstd*g[col] + bb[col];
    if (of) of[base + col] = y;
    if (ob) ob[base + col] = f2bf(y);
  }
}

// ---------------- driver ----------------
extern "C" void kernel_launch(void* const* d_in, const int* in_sizes, int n_in,
                              void* d_out, int out_size, void* d_ws, size_t ws_size,
                              hipStream_t stream)
{
  const float* tgt      = (const float*)d_in[0];
  const float* mem      = (const float*)d_in[1];
  const float* sa_w_in  = (const float*)d_in[2];
  const float* sa_b_in  = (const float*)d_in[3];
  const float* sa_w_out = (const float*)d_in[4];
  const float* sa_b_out = (const float*)d_in[5];
  const float* ca_w_in  = (const float*)d_in[6];
  const float* ca_b_in  = (const float*)d_in[7];
  const float* ca_w_out = (const float*)d_in[8];
  const float* ca_b_out = (const float*)d_in[9];
  const float* w1 = (const float*)d_in[10];
  const float* b1 = (const float*)d_in[11];
  const float* w2 = (const float*)d_in[12];
  const float* b2 = (const float*)d_in[13];
  const float* ln1_g=(const float*)d_in[14]; const float* ln1_b=(const float*)d_in[15];
  const float* ln2_g=(const float*)d_in[16]; const float* ln2_b=(const float*)d_in[17];
  const float* ln3_g=(const float*)d_in[18]; const float* ln3_b=(const float*)d_in[19];

  char* ws = (char*)d_ws;
  size_t off = 0;
  auto alloc = [&](size_t bytes)->char* {
    char* p = ws + off; off += (bytes + 255) & ~(size_t)255; return p;
  };
  unsigned short* w_sa_in_b  = (unsigned short*)alloc((size_t)3*E_*E_*2);
  unsigned short* w_sa_out_b = (unsigned short*)alloc((size_t)E_*E_*2);
  unsigned short* w_ca_in_b  = (unsigned short*)alloc((size_t)3*E_*E_*2);
  unsigned short* w_ca_out_b = (unsigned short*)alloc((size_t)E_*E_*2);
  unsigned short* w1_b  = (unsigned short*)alloc((size_t)FF_*E_*2);
  unsigned short* w2_b  = (unsigned short*)alloc((size_t)E_*FF_*2);
  unsigned short* tgt_b = (unsigned short*)alloc((size_t)M1_*E_*2);
  unsigned short* mem_b = (unsigned short*)alloc((size_t)M2_*E_*2);
  unsigned short* qbuf  = (unsigned short*)alloc((size_t)64*T_*HD_*2);
  unsigned short* kbuf  = (unsigned short*)alloc((size_t)64*S_*HD_*2);
  unsigned short* vtbuf = (unsigned short*)alloc((size_t)64*S_*HD_*2);
  unsigned short* cbuf  = (unsigned short*)alloc((size_t)M1_*FF_*2);
  unsigned short* atto  = (unsigned short*)alloc((size_t)M1_*E_*2);
  unsigned short* opart = (unsigned short*)alloc((size_t)2*64*T_*HD_*2);  // also reused as f32 P1 (16 MB)
  float*          lpart = (float*)alloc((size_t)2*64*T_*4);
  float* resf = (float*)alloc((size_t)M1_*E_*4);
  float* xf   = (float*)alloc((size_t)M1_*E_*4);
  unsigned short* xb = (unsigned short*)alloc((size_t)M1_*E_*2);
  (void)ws_size; (void)in_sizes; (void)n_in; (void)out_size;

  float* P1 = (float*)opart;   // 2*64*1024*64*2 B == M1_*E_*4 B exactly

  const float QSCALE = 0.125f * LOG2E;   // fold log2e into q so P = exp2(score)

  // ---- fused input/weight conversion (one launch) ----
  {
    CvtArgs a;
    const float* srcs[8] = {tgt, mem, sa_w_in, sa_w_out, ca_w_in, ca_w_out, w1, w2};
    unsigned short* dsts[8] = {tgt_b, mem_b, w_sa_in_b, w_sa_out_b, w_ca_in_b, w_ca_out_b, w1_b, w2_b};
    size_t ns[8] = {(size_t)M1_*E_, (size_t)M2_*E_, (size_t)3*E_*E_, (size_t)E_*E_,
                    (size_t)3*E_*E_, (size_t)E_*E_, (size_t)FF_*E_, (size_t)E_*FF_};
    int blk = 0;
    for (int i=0;i<8;i++){
      a.seg[i].s = srcs[i]; a.seg[i].d = dsts[i]; a.seg[i].n4 = (int)(ns[i]/4);
      blk += (a.seg[i].n4 + 255)/256;
      a.blk_end[i] = blk;
    }
    f2b_multi_k<<<blk, 256, 0, stream>>>(a);
  }

  // ---- self-attention block ----
  gemm8_k<0,1><<<(M1_/256)*((3*E_)/256), 512, 0, stream>>>(
      tgt_b, E_, w_sa_in_b, E_, sa_b_in, nullptr, qbuf, kbuf, vtbuf,
      M1_, 3*E_, E_, E_, E_, T_, T_, QSCALE);
  attn_k<false,16><<<dim3(64, T_/128, 1), 256, 0, stream>>>(
      qbuf, kbuf, vtbuf, atto, nullptr, T_, T_);
  gemm_splitk_k<64><<<dim3(M1_/128, E_/64, 2), 256, 0, stream>>>(
      atto, E_, w_sa_out_b, E_, sa_b_out, tgt, resf, P1, M1_, E_, E_);
  ln_k<<<M1_, 256, 0, stream>>>(resf, P1, ln1_g, ln1_b, xf, xb);

  // ---- cross-attention block ----
  gemm8_k<0,1><<<(M2_/256)*((2*E_)/256), 512, 0, stream>>>(
      mem_b, E_, w_ca_in_b + (size_t)E_*E_, E_, ca_b_in + E_, nullptr,
      nullptr, kbuf, vtbuf,
      M2_, 2*E_, E_, 0, E_, S_, S_, QSCALE);
  gemm_scat_k<64><<<dim3(M1_/128, E_/64), 256, 0, stream>>>(
      xb, E_, w_ca_in_b, E_, ca_b_in, qbuf, nullptr, nullptr,
      M1_, E_, E_, E_, 0, T_, S_, QSCALE);
  attn_k<true,16><<<dim3(64, T_/128, 2), 256, 0, stream>>>(
      qbuf, kbuf, vtbuf, opart, lpart, T_, S_);
  comb_k<<<dim3(T_/4, 64), 256, 0, stream>>>(opart, lpart, atto, T_);
  gemm_splitk_k<64><<<dim3(M1_/128, E_/64, 2), 256, 0, stream>>>(
      atto, E_, w_ca_out_b, E_, ca_b_out, xf, resf, P1, M1_, E_, E_);
  ln_k<<<M1_, 256, 0, stream>>>(resf, P1, ln2_g, ln2_b, xf, xb);

  // ---- FFN ----
  gemm8_k<5,0><<<(M1_/256)*(FF_/256), 512, 0, stream>>>(
      xb, E_, w1_b, E_, b1, cbuf, nullptr, nullptr, nullptr,
      M1_, FF_, E_, 0, 0, 0, 0, 0.f);
  gemm_splitk_k<64><<<dim3(M1_/128, E_/64, 2), 256, 0, stream>>>(
      cbuf, FF_, w2_b, FF_, b2, xf, resf, P1, M1_, E_, FF_);
  ln_k<<<M1_, 256, 0, stream>>>(resf, P1, ln3_g, ln3_b, (float*)d_out, nullptr);
}